// Round 4
// baseline (1457.378 us; speedup 1.0000x reference)
//
#include <hip/hip_runtime.h>
#include <cstdint>
#include <cstddef>

// ---------------- constants ----------------
#define BATCH   32768
#define NBLK    (BATCH/4)    // 8192 blocks, 4 waves/block, 1 sample/wave

// d_ws byte offsets (bf16 transposed weights + collapsed MLP)
#define WS_WIN   0            // [128][128] bf16  WinT[n][k] = W_in[k][n]
#define WS_WQKV  32768        // [384][128] bf16
#define WS_WC    131072       // [128][128] bf16  (W_m1 @ W_m2)^T
#define WS_WGI   163840       // [256][128] bf16
#define WS_WGM   229376       // [256][128] bf16
#define WS_BC    294912       // [128] f32        b_m1 @ W_m2 + b_m2

// per-wave LDS slab: 11008 B. Block: 4*11008 = 44032 B -> 3 blocks/CU.
#define SLAB   11008
#define LDSSZ  44032

typedef __bf16 bf16x8 __attribute__((ext_vector_type(8)));
typedef __bf16 bf16x4 __attribute__((ext_vector_type(4)));
typedef float  f32x4  __attribute__((ext_vector_type(4)));

__device__ __forceinline__ float sigmoidf_(float x){ return 1.f/(1.f+__expf(-x)); }
__device__ __forceinline__ float tanhf_(float x){ float e = __expf(2.f*x); return 1.f - 2.f/(e+1.f); }

// XOR bank swizzle: permute 16B blocks within each row by row&7.
// Accesses of <=16B at 16B-block-preserving offsets stay inside one block.
__device__ __forceinline__ char* swz(char* base, int row, int stride, int colb){
  return base + row*stride + (colb ^ ((row & 7) << 4));
}

// ---------------- weight prep: f32 -> bf16 transposed, W_m1@W_m2 collapsed ----------------
__global__ __launch_bounds__(256) void prep_kernel(
    const float* __restrict__ W_in,  const float* __restrict__ W_qkv,
    const float* __restrict__ W_m1,  const float* __restrict__ W_m2,
    const float* __restrict__ b_m1,  const float* __restrict__ b_m2,
    const float* __restrict__ W_gi,  const float* __restrict__ W_gm,
    __bf16* __restrict__ ws, float* __restrict__ bc)
{
  int gt = blockIdx.x*256 + threadIdx.x;
  int NT = gridDim.x*256;
  for (int i = gt; i < 128*128; i += NT){ int n=i>>7, k=i&127; ws[(WS_WIN >>1)+i] = (__bf16)W_in [k*128+n]; }
  for (int i = gt; i < 384*128; i += NT){ int n=i>>7, k=i&127; ws[(WS_WQKV>>1)+i] = (__bf16)W_qkv[k*384+n]; }
  for (int i = gt; i < 256*128; i += NT){ int n=i>>7, k=i&127; ws[(WS_WGI >>1)+i] = (__bf16)W_gi [k*256+n]; }
  for (int i = gt; i < 256*128; i += NT){ int n=i>>7, k=i&127; ws[(WS_WGM >>1)+i] = (__bf16)W_gm [k*256+n]; }
  for (int i = gt; i < 128*128; i += NT){
    int n=i>>7, k=i&127;
    float s = 0.f;
    for (int j=0;j<128;j++) s += W_m1[k*128+j]*W_m2[j*128+n];
    ws[(WS_WC>>1)+i] = (__bf16)s;
  }
  for (int i = gt; i < 128; i += NT){
    float s = b_m2[i];
    for (int j=0;j<128;j++) s += b_m1[j]*W_m2[j*128+i];
    bc[i] = s;
  }
}

// ---------------- fused main kernel: one WAVE owns one sample, barrier-free ----------------
// Per-wave slab layout (11008 B):
//  MP  [0,4096)    : bf16 [16 rows][256B] swz. mp slots 0..7 + x(row 8); later mem; later tanh(memory).
//  PT  @2304       : attn P [4h][9 rows][32B]
//  GI  @2304       : gi f32[256] (after attention, aliases PT)
//  XT  @3840       : x bf16[128] (row 0 of a virtual 16-row A-tile)
//  QK  [4096,11008): bf16 [9 rows][768B] swz = qkv; attn-out overwrites q-slices;
//                    later mlp f32 [9][512B] swz @+0, mem2 bf16 [8][256B] swz @+4608.
// DETERMINISM INVARIANT: every LDS byte any instruction READS is WRITTEN earlier in
// program order by the same wave in the same kernel call (P0 zero-fills all scratch,
// P4 clamps fragment rows to <=8). No cross-wave traffic, no read of leftover LDS,
// hence no barrier and bit-identical results on every call.
__global__ __launch_bounds__(256, 3) void rmc_kernel(
    const float* __restrict__ inputs, const float* __restrict__ memory,
    const float* __restrict__ b_in,   const float* __restrict__ b_qkv,
    const float* __restrict__ lnq_g,  const float* __restrict__ lnq_b,
    const float* __restrict__ ln1_g,  const float* __restrict__ ln1_b,
    const float* __restrict__ ln2_g,  const float* __restrict__ ln2_b,
    const float* __restrict__ b_gi,   const float* __restrict__ b_gm,
    const __bf16* __restrict__ wWin,  const __bf16* __restrict__ wWqkv,
    const __bf16* __restrict__ wWc,   const __bf16* __restrict__ wWgi,
    const __bf16* __restrict__ wWgm,  const float* __restrict__ bc,
    float* __restrict__ out0, float* __restrict__ out1)
{
  __shared__ __align__(16) char smem[LDSSZ];
  const int tid  = threadIdx.x;
  const int lane = tid & 63;
  const int wv   = tid >> 6;
  const int l15  = lane & 15;
  const int lg   = lane >> 4;
  const int s    = blockIdx.x*4 + wv;
  const float QSC = 0.1020620726159658f;   // 96^-0.5

  char* SL = smem + wv*SLAB;
  char* MP = SL;
  char* PT = SL + 2304;
  char* GI = SL + 2304;
  char* XT = SL + 3840;
  char* QK = SL + 4096;

  // ---- P0a: zero ALL scratch bytes this wave will ever read before writing ----
  // [2304, 11008) = MP rows 9..15 (incl. PT/GI/XT) + whole QK region: 8704 B = 544 x 16B
  for (int i = lane; i < 544; i += 64)
    *(f32x4*)(SL + 2304 + i*16) = (f32x4){0.f,0.f,0.f,0.f};

  // ---- P0b: stage x-input row + memory rows (wave-private) ----
  if (lane < 32){
    f32x4 v = *(const f32x4*)(inputs + (size_t)s*128 + lane*4);
    bf16x4 h; h[0]=(__bf16)v[0]; h[1]=(__bf16)v[1]; h[2]=(__bf16)v[2]; h[3]=(__bf16)v[3];
    *(bf16x4*)(XT + lane*8) = h;
  }
#pragma unroll
  for (int it=0; it<4; ++it){
    int e0 = it*256 + lane*4, row = e0>>7, col = e0&127;
    f32x4 v = *(const f32x4*)(memory + (size_t)s*1024 + e0);
    bf16x4 h; h[0]=(__bf16)v[0]; h[1]=(__bf16)v[1]; h[2]=(__bf16)v[2]; h[3]=(__bf16)v[3];
    *(bf16x4*)swz(MP, row, 256, col*2) = h;
  }

  // ---- P1: x = inputs @ W_in + b_in  (M=1 valid row) ----
  {
    bf16x8 a[4];
#pragma unroll
    for (int k=0;k<4;k++) a[k] = *(const bf16x8*)swz(XT, l15, 256, k*64 + lg*16);
#pragma unroll
    for (int nt=0; nt<8; ++nt){
      f32x4 acc = {0.f,0.f,0.f,0.f};
#pragma unroll
      for (int k=0;k<4;k++){
        bf16x8 b = *(const bf16x8*)(wWin + (nt*16 + l15)*128 + k*32 + lg*8);
        acc = __builtin_amdgcn_mfma_f32_16x16x32_bf16(a[k], b, acc, 0, 0, 0);
      }
      if (lg == 0){              // row 0 = (lg=0, r=0)
        int c = nt*16 + l15;
        __bf16 h = (__bf16)(acc[0] + b_in[c]);
        *(__bf16*)swz(MP, 8, 256, c*2) = h;   // mp slot 8
        *(__bf16*)(XT + c*2) = h;             // x copy for gi GEMM
      }
    }
  }

  // ---- P2: qkv = mp @ W_qkv + b_qkv  (9 valid rows, N=384) ----
  {
    bf16x8 a[4];
#pragma unroll
    for (int k=0;k<4;k++) a[k] = *(const bf16x8*)swz(MP, l15, 256, k*64 + lg*16);
#pragma unroll
    for (int nt=0; nt<24; ++nt){
      f32x4 acc = {0.f,0.f,0.f,0.f};
#pragma unroll
      for (int k=0;k<4;k++){
        bf16x8 b = *(const bf16x8*)(wWqkv + (nt*16 + l15)*128 + k*32 + lg*8);
        acc = __builtin_amdgcn_mfma_f32_16x16x32_bf16(a[k], b, acc, 0, 0, 0);
      }
      int c = nt*16 + l15;
      float bq = b_qkv[c];
#pragma unroll
      for (int r=0;r<4;r++){
        int row = 4*lg + r;
        if (row < 9) *(__bf16*)swz(QK, row, 768, c*2) = (__bf16)(acc[r] + bq);
      }
    }
  }

  // ---- P3: LN(qkv) in place + fold q-scale ----
  {
    auto ln384 = [&](int r, int j){
      float x[48]; float sm=0.f, sq=0.f;
#pragma unroll
      for (int t=0;t<6;t++){
        bf16x8 h = *(const bf16x8*)swz(QK, r, 768, j*96 + t*16);
#pragma unroll
        for (int e=0;e<8;e++){ float f=(float)h[e]; x[t*8+e]=f; sm+=f; sq+=f*f; }
      }
#pragma unroll
      for (int o=1;o<8;o<<=1){ sm += __shfl_xor(sm,o); sq += __shfl_xor(sq,o); }
      float mean = sm*(1.f/384.f), var = sq*(1.f/384.f)-mean*mean, rs = rsqrtf(var+1e-5f);
      int jodd = j & 1;
#pragma unroll
      for (int t=0;t<6;t++){
        int cb = j*48 + t*8;
        f32x4 g0 = *(const f32x4*)(lnq_g+cb), g1 = *(const f32x4*)(lnq_g+cb+4);
        f32x4 e0 = *(const f32x4*)(lnq_b+cb), e1 = *(const f32x4*)(lnq_b+cb+4);
        bf16x8 h;
#pragma unroll
        for (int e=0;e<8;e++){
          float gg = (e<4) ? g0[e] : g1[e-4];
          float bb = (e<4) ? e0[e] : e1[e-4];
          float y = gg*(x[t*8+e]-mean)*rs + bb;
          if (!jodd && (t*8+e) < 32) y *= QSC;   // (c%96)<32
          h[e] = (__bf16)y;
        }
        *(bf16x8*)swz(QK, r, 768, j*96 + t*16) = h;
      }
    };
    ln384(lane>>3, lane&7);
    if (lane < 8) ln384(8, lane);
  }

  // ---- P4: attention. QK^T via 4 MFMA (K=32), shuffle softmax, PV via VALU ----
  {
    const int arow = (l15 < 9) ? l15 : 8;   // clamp: never read past row 8 (in-slab, valid)
    f32x4 sc[4];
#pragma unroll
    for (int h=0;h<4;h++){
      bf16x8 qa = *(const bf16x8*)swz(QK, arow, 768, h*192 + lg*16);
      bf16x8 kb = *(const bf16x8*)swz(QK, arow, 768, h*192 + 64 + lg*16);
      sc[h] = __builtin_amdgcn_mfma_f32_16x16x32_bf16(qa, kb, (f32x4){0.f,0.f,0.f,0.f}, 0, 0, 0);
    }
#pragma unroll
    for (int h=0;h<4;h++){
#pragma unroll
      for (int r=0;r<4;r++){
        int row = 4*lg + r;                       // q index
        float v = (l15 < 9) ? sc[h][r] : -1e30f;  // mask duplicate/pad k columns
        float mx = v;
#pragma unroll
        for (int o=1;o<16;o<<=1) mx = fmaxf(mx, __shfl_xor(mx, o));
        float p = __expf(v - mx);
        float sm = p;
#pragma unroll
        for (int o=1;o<16;o<<=1) sm += __shfl_xor(sm, o);
        float pn = p / sm;
        if (row < 9) *(__bf16*)(PT + h*288 + row*32 + l15*2) = (__bf16)pn;
      }
    }
    // PV: 144 tasks = (q 0..8) x (16 8-col chunks)
#pragma unroll
    for (int pass=0; pass<3; ++pass){
      int t = pass*64 + lane;
      if (t < 144){
        int q = t>>4, ch = t&15, h = ch>>2, d16 = (ch&3)*16;
        float o8[8] = {0.f,0.f,0.f,0.f,0.f,0.f,0.f,0.f};
#pragma unroll
        for (int k=0;k<9;k++){
          float p = (float)*(const __bf16*)(PT + h*288 + q*32 + k*2);
          bf16x8 v8 = *(const bf16x8*)swz(QK, k, 768, h*192 + 128 + d16);
#pragma unroll
          for (int e=0;e<8;e++) o8[e] += p*(float)v8[e];
        }
        bf16x8 ho;
#pragma unroll
        for (int e=0;e<8;e++) ho[e] = (__bf16)o8[e];
        *(bf16x8*)swz(QK, q, 768, h*192 + d16) = ho;   // out -> dead q-slice
      }
    }
  }

  // ---- P5: mem = LN(mp + out) -> MP (in place) ----
  {
    auto ln1 = [&](int r, int j){
      bf16x8 m0 = *(const bf16x8*)swz(MP, r, 256, j*32);
      bf16x8 m1 = *(const bf16x8*)swz(MP, r, 256, j*32 + 16);
      int ob = (j>>1)*192 + (j&1)*32;
      bf16x8 o0 = *(const bf16x8*)swz(QK, r, 768, ob);
      bf16x8 o1 = *(const bf16x8*)swz(QK, r, 768, ob + 16);
      float tv[16]; float sm=0.f, sq=0.f;
#pragma unroll
      for (int e=0;e<8;e++){
        float a = (float)m0[e] + (float)o0[e]; tv[e]   = a; sm += a; sq += a*a;
        float b = (float)m1[e] + (float)o1[e]; tv[8+e] = b; sm += b; sq += b*b;
      }
#pragma unroll
      for (int o=1;o<8;o<<=1){ sm += __shfl_xor(sm,o); sq += __shfl_xor(sq,o); }
      float mean = sm*(1.f/128.f), var = sq*(1.f/128.f)-mean*mean, rs = rsqrtf(var+1e-5f);
      int cb = j*16;
      f32x4 g0 = *(const f32x4*)(ln1_g+cb),   g1 = *(const f32x4*)(ln1_g+cb+4);
      f32x4 g2 = *(const f32x4*)(ln1_g+cb+8), g3 = *(const f32x4*)(ln1_g+cb+12);
      f32x4 e0 = *(const f32x4*)(ln1_b+cb),   e1 = *(const f32x4*)(ln1_b+cb+4);
      f32x4 e2 = *(const f32x4*)(ln1_b+cb+8), e3 = *(const f32x4*)(ln1_b+cb+12);
      bf16x8 h0, h1;
#pragma unroll
      for (int e=0;e<8;e++){
        float ga = (e<4)?g0[e]:g1[e-4], ba = (e<4)?e0[e]:e1[e-4];
        float gb = (e<4)?g2[e]:g3[e-4], bb = (e<4)?e2[e]:e3[e-4];
        h0[e] = (__bf16)(ga*(tv[e]  -mean)*rs + ba);
        h1[e] = (__bf16)(gb*(tv[8+e]-mean)*rs + bb);
      }
      *(bf16x8*)swz(MP, r, 256, j*32)      = h0;
      *(bf16x8*)swz(MP, r, 256, j*32 + 16) = h1;
    };
    ln1(lane>>3, lane&7);
    if (lane < 8) ln1(8, lane);
  }

  // ---- P6: mlp = mem @ (W_m1 W_m2) + bc -> QK region as f32 [9][512B] swz ----
  {
    bf16x8 a[4];
#pragma unroll
    for (int k=0;k<4;k++) a[k] = *(const bf16x8*)swz(MP, l15, 256, k*64 + lg*16);
#pragma unroll
    for (int nt=0; nt<8; ++nt){
      f32x4 acc = {0.f,0.f,0.f,0.f};
#pragma unroll
      for (int k=0;k<4;k++){
        bf16x8 b = *(const bf16x8*)(wWc + (nt*16 + l15)*128 + k*32 + lg*8);
        acc = __builtin_amdgcn_mfma_f32_16x16x32_bf16(a[k], b, acc, 0, 0, 0);
      }
      int c = nt*16 + l15;
      float bcv = bc[c];
#pragma unroll
      for (int r=0;r<4;r++){
        int row = 4*lg + r;
        if (row < 9) *(float*)swz(QK, row, 512, c*4) = acc[r] + bcv;
      }
    }
  }

  // ---- P7: mem2 = LN(mlp + mem), rows 0..7 only -> QK+4608 bf16 [8][256B] swz ----
  {
    int r = lane>>3, j = lane&7;
    f32x4 p0 = *(const f32x4*)swz(QK, r, 512, j*64);
    f32x4 p1 = *(const f32x4*)swz(QK, r, 512, j*64 + 16);
    f32x4 p2 = *(const f32x4*)swz(QK, r, 512, j*64 + 32);
    f32x4 p3 = *(const f32x4*)swz(QK, r, 512, j*64 + 48);
    bf16x8 m0 = *(const bf16x8*)swz(MP, r, 256, j*32);
    bf16x8 m1 = *(const bf16x8*)swz(MP, r, 256, j*32 + 16);
    float tv[16]; float sm=0.f, sq=0.f;
#pragma unroll
    for (int e=0;e<8;e++){
      float a = ((e<4)?p0[e]:p1[e-4]) + (float)m0[e]; tv[e]   = a; sm += a; sq += a*a;
      float b = ((e<4)?p2[e]:p3[e-4]) + (float)m1[e]; tv[8+e] = b; sm += b; sq += b*b;
    }
#pragma unroll
    for (int o=1;o<8;o<<=1){ sm += __shfl_xor(sm,o); sq += __shfl_xor(sq,o); }
    float mean = sm*(1.f/128.f), var = sq*(1.f/128.f)-mean*mean, rs = rsqrtf(var+1e-5f);
    int cb = j*16;
    f32x4 g0 = *(const f32x4*)(ln2_g+cb),   g1 = *(const f32x4*)(ln2_g+cb+4);
    f32x4 g2 = *(const f32x4*)(ln2_g+cb+8), g3 = *(const f32x4*)(ln2_g+cb+12);
    f32x4 e0 = *(const f32x4*)(ln2_b+cb),   e1 = *(const f32x4*)(ln2_b+cb+4);
    f32x4 e2 = *(const f32x4*)(ln2_b+cb+8), e3 = *(const f32x4*)(ln2_b+cb+12);
    bf16x8 h0, h1;
#pragma unroll
    for (int e=0;e<8;e++){
      float ga = (e<4)?g0[e]:g1[e-4], ba = (e<4)?e0[e]:e1[e-4];
      float gb = (e<4)?g2[e]:g3[e-4], bb = (e<4)?e2[e]:e3[e-4];
      h0[e] = (__bf16)(ga*(tv[e]  -mean)*rs + ba);
      h1[e] = (__bf16)(gb*(tv[8+e]-mean)*rs + bb);
    }
    *(bf16x8*)swz(QK + 4608, r, 256, j*32)      = h0;
    *(bf16x8*)swz(QK + 4608, r, 256, j*32 + 16) = h1;
  }

  // ---- P8: gi = x @ W_gi + b_gi -> GI f32[256]; tanh(memory) -> MP rows 0..7 ----
  {
    bf16x8 a[4];
#pragma unroll
    for (int k=0;k<4;k++) a[k] = *(const bf16x8*)swz(XT, l15, 256, k*64 + lg*16);
#pragma unroll
    for (int nt=0; nt<16; ++nt){
      f32x4 acc = {0.f,0.f,0.f,0.f};
#pragma unroll
      for (int k=0;k<4;k++){
        bf16x8 b = *(const bf16x8*)(wWgi + (nt*16 + l15)*128 + k*32 + lg*8);
        acc = __builtin_amdgcn_mfma_f32_16x16x32_bf16(a[k], b, acc, 0, 0, 0);
      }
      if (lg == 0){
        int c = nt*16 + l15;
        *(float*)(GI + c*4) = acc[0] + b_gi[c];
      }
    }
#pragma unroll
    for (int it=0; it<4; ++it){
      int e0 = it*256 + lane*4, row = e0>>7, col = e0&127;
      f32x4 v = *(const f32x4*)(memory + (size_t)s*1024 + e0);
      bf16x4 h; h[0]=(__bf16)tanhf_(v[0]); h[1]=(__bf16)tanhf_(v[1]);
                h[2]=(__bf16)tanhf_(v[2]); h[3]=(__bf16)tanhf_(v[3]);
      *(bf16x4*)swz(MP, row, 256, col*2) = h;
    }
  }

  // ---- P9: gm = tanh(memory) @ W_gm + b_gm; fused gates -> global ----
  {
    bf16x8 a[4];
#pragma unroll
    for (int k=0;k<4;k++) a[k] = *(const bf16x8*)swz(MP, l15, 256, k*64 + lg*16);
#pragma unroll
    for (int p=0; p<8; ++p){
      f32x4 ai = {0.f,0.f,0.f,0.f}, af = {0.f,0.f,0.f,0.f};
#pragma unroll
      for (int k=0;k<4;k++){
        bf16x8 bi = *(const bf16x8*)(wWgm + ((p  )*16 + l15)*128 + k*32 + lg*8);
        bf16x8 bf = *(const bf16x8*)(wWgm + ((p+8)*16 + l15)*128 + k*32 + lg*8);
        ai = __builtin_amdgcn_mfma_f32_16x16x32_bf16(a[k], bi, ai, 0, 0, 0);
        af = __builtin_amdgcn_mfma_f32_16x16x32_bf16(a[k], bf, af, 0, 0, 0);
      }
      int c = p*16 + l15;
      float giv = *(const float*)(GI + c*4);
      float gfv = *(const float*)(GI + (128+c)*4);
      float bgi = b_gm[c], bgf = b_gm[128+c];
#pragma unroll
      for (int r=0;r<4;r++){
        int row = 4*lg + r;            // slot j
        if (row < 8){
          float g_i = ai[r] + bgi + giv;
          float g_f = af[r] + bgf + gfv + 1.0f;
          float ig = sigmoidf_(g_i), fg = sigmoidf_(g_f);
          float m2 = (float)*(const __bf16*)swz(QK + 4608, row, 256, c*2);
          float mo = memory[(size_t)s*1024 + row*128 + c];
          float nm = ig*tanhf_(m2) + fg*mo;
          size_t o = (size_t)s*1024 + (size_t)(row*128 + c);
          out0[o] = nm;
          out1[o] = nm;
        }
      }
    }
  }
}

// ---------------- launch ----------------
extern "C" void kernel_launch(void* const* d_in, const int* in_sizes, int n_in,
                              void* d_out, int out_size, void* d_ws, size_t ws_size,
                              hipStream_t stream) {
  const float* inputs = (const float*)d_in[0];
  const float* memory = (const float*)d_in[1];
  const float* W_in   = (const float*)d_in[2];
  const float* b_in   = (const float*)d_in[3];
  const float* W_qkv  = (const float*)d_in[4];
  const float* b_qkv  = (const float*)d_in[5];
  const float* lnq_g  = (const float*)d_in[6];
  const float* lnq_b  = (const float*)d_in[7];
  const float* ln1_g  = (const float*)d_in[8];
  const float* ln1_b  = (const float*)d_in[9];
  const float* W_m1   = (const float*)d_in[10];
  const float* b_m1   = (const float*)d_in[11];
  const float* W_m2   = (const float*)d_in[12];
  const float* b_m2   = (const float*)d_in[13];
  const float* ln2_g  = (const float*)d_in[14];
  const float* ln2_b  = (const float*)d_in[15];
  const float* W_gi   = (const float*)d_in[16];
  const float* b_gi   = (const float*)d_in[17];
  const float* W_gm   = (const float*)d_in[18];
  const float* b_gm   = (const float*)d_in[19];

  __bf16* ws16 = (__bf16*)d_ws;
  float* bcp = (float*)((char*)d_ws + WS_BC);
  const __bf16* wWin  = (const __bf16*)((char*)d_ws + WS_WIN);
  const __bf16* wWqkv = (const __bf16*)((char*)d_ws + WS_WQKV);
  const __bf16* wWc   = (const __bf16*)((char*)d_ws + WS_WC);
  const __bf16* wWgi  = (const __bf16*)((char*)d_ws + WS_WGI);
  const __bf16* wWgm  = (const __bf16*)((char*)d_ws + WS_WGM);

  float* out0 = (float*)d_out;
  float* out1 = out0 + (size_t)BATCH*1024;

  prep_kernel<<<dim3(256), dim3(256), 0, stream>>>(
      W_in, W_qkv, W_m1, W_m2, b_m1, b_m2, W_gi, W_gm, ws16, bcp);

  rmc_kernel<<<dim3(NBLK), dim3(256), 0, stream>>>(
      inputs, memory, b_in, b_qkv, lnq_g, lnq_b, ln1_g, ln1_b, ln2_g, ln2_b,
      b_gi, b_gm, wWin, wWqkv, wWc, wWgi, wWgm, bcp, out0, out1);
}

// Round 5
// 1456.144 us; speedup vs baseline: 1.0008x; 1.0008x over previous
//
#include <hip/hip_runtime.h>
#include <cstdint>
#include <cstddef>

// ---------------- constants ----------------
#define BATCH   32768
#define NBLK    (BATCH/4)    // 8192 blocks, 4 waves/block, 1 sample/wave

// d_ws byte offsets (bf16 transposed weights + collapsed MLP)
#define WS_WIN   0            // [128][128] bf16  WinT[n][k] = W_in[k][n]
#define WS_WQKV  32768        // [384][128] bf16
#define WS_WC    131072       // [128][128] bf16  (W_m1 @ W_m2)^T
#define WS_WGI   163840       // [256][128] bf16
#define WS_WGM   229376       // [256][128] bf16
#define WS_BC    294912       // [128] f32        b_m1 @ W_m2 + b_m2

// per-wave LDS slab: 10240 B -> block 40960 B -> EXACTLY 4 blocks/CU (160 KiB).
#define SLAB   10240
#define LDSSZ  40960

typedef __bf16 bf16x8 __attribute__((ext_vector_type(8)));
typedef __bf16 bf16x4 __attribute__((ext_vector_type(4)));
typedef float  f32x4  __attribute__((ext_vector_type(4)));

__device__ __forceinline__ float sigmoidf_(float x){ return 1.f/(1.f+__expf(-x)); }
__device__ __forceinline__ float tanhf_(float x){ float e = __expf(2.f*x); return 1.f - 2.f/(e+1.f); }

// XOR bank swizzle: permute 16B blocks within each row by row&7.
__device__ __forceinline__ char* swz(char* base, int row, int stride, int colb){
  return base + row*stride + (colb ^ ((row & 7) << 4));
}

// Depth-1 software-pipelined weight GEMM: B-frags for nt+1 load while nt's MFMAs run.
// All indexing compile-time after unroll (no scratch).
template<int NT, typename FC>
__device__ __forceinline__ void gemmW(const __bf16* __restrict__ W,
                                      const bf16x8 (&a)[4], const int l15, const int lg,
                                      FC consume){
  bf16x8 b0[4], b1[4];
#pragma unroll
  for (int k=0;k<4;k++) b0[k] = *(const bf16x8*)(W + l15*128 + k*32 + lg*8);
#pragma unroll
  for (int nt=0; nt<NT; ++nt){
    if (nt+1 < NT){
      const __bf16* Wn = W + (nt+1)*16*128;
      if ((nt&1)==0){
#pragma unroll
        for (int k=0;k<4;k++) b1[k] = *(const bf16x8*)(Wn + l15*128 + k*32 + lg*8);
      } else {
#pragma unroll
        for (int k=0;k<4;k++) b0[k] = *(const bf16x8*)(Wn + l15*128 + k*32 + lg*8);
      }
    }
    f32x4 acc = {0.f,0.f,0.f,0.f};
    if ((nt&1)==0){
#pragma unroll
      for (int k=0;k<4;k++) acc = __builtin_amdgcn_mfma_f32_16x16x32_bf16(a[k], b0[k], acc, 0,0,0);
    } else {
#pragma unroll
      for (int k=0;k<4;k++) acc = __builtin_amdgcn_mfma_f32_16x16x32_bf16(a[k], b1[k], acc, 0,0,0);
    }
    consume(nt, acc);
  }
}

// ---------------- weight prep: f32 -> bf16 transposed, W_m1@W_m2 collapsed ----------------
__global__ __launch_bounds__(256) void prep_kernel(
    const float* __restrict__ W_in,  const float* __restrict__ W_qkv,
    const float* __restrict__ W_m1,  const float* __restrict__ W_m2,
    const float* __restrict__ b_m1,  const float* __restrict__ b_m2,
    const float* __restrict__ W_gi,  const float* __restrict__ W_gm,
    __bf16* __restrict__ ws, float* __restrict__ bc)
{
  int gt = blockIdx.x*256 + threadIdx.x;
  int NT = gridDim.x*256;
  for (int i = gt; i < 128*128; i += NT){ int n=i>>7, k=i&127; ws[(WS_WIN >>1)+i] = (__bf16)W_in [k*128+n]; }
  for (int i = gt; i < 384*128; i += NT){ int n=i>>7, k=i&127; ws[(WS_WQKV>>1)+i] = (__bf16)W_qkv[k*384+n]; }
  for (int i = gt; i < 256*128; i += NT){ int n=i>>7, k=i&127; ws[(WS_WGI >>1)+i] = (__bf16)W_gi [k*256+n]; }
  for (int i = gt; i < 256*128; i += NT){ int n=i>>7, k=i&127; ws[(WS_WGM >>1)+i] = (__bf16)W_gm [k*256+n]; }
  for (int i = gt; i < 128*128; i += NT){
    int n=i>>7, k=i&127;
    float s = 0.f;
    for (int j=0;j<128;j++) s += W_m1[k*128+j]*W_m2[j*128+n];
    ws[(WS_WC>>1)+i] = (__bf16)s;
  }
  for (int i = gt; i < 128; i += NT){
    float s = b_m2[i];
    for (int j=0;j<128;j++) s += b_m1[j]*W_m2[j*128+i];
    bc[i] = s;
  }
}

// ---------------- fused main kernel: one WAVE owns one sample, barrier-free ----------------
// Per-wave slab (10240 B):
//  MP [0,3328)     : bf16 13 rows x 256B swz. rows 0..8 = mp (later mem, later tanh(memory));
//                    rows 9..12 scratch: GI f32[256] @+2304 (1024B), XT bf16[128] @+3072
//                    (aliases GI floats 192..255; GI written after XT dead).
//  QK [3328,10240) : bf16 [9 rows][768B] swz = qkv. P-matrix + attn-out overwrite dead
//                    q-slices. Later: mlp f32 [9][512]@+0; mem2 bf16 [8][256]@+4608;
//                    memf f32 [8][512]@+0 (P8); nm written in-place over memf (P9).
// DETERMINISM: every LDS byte read is written earlier in program order by the same wave
// this call (P0 zero-fills the only pre-write-read spans; attention A-rows clamped <=8;
// A-tile overreads into later rows hit deterministic data and only feed discarded C rows).
// X-GEMMs (P1/P8) use an all-lanes-broadcast 256B A-row (every C row equals x@W).
__global__ __launch_bounds__(256, 4) void rmc_kernel(
    const float* __restrict__ inputs, const float* __restrict__ memory,
    const float* __restrict__ b_in,   const float* __restrict__ b_qkv,
    const float* __restrict__ lnq_g,  const float* __restrict__ lnq_b,
    const float* __restrict__ ln1_g,  const float* __restrict__ ln1_b,
    const float* __restrict__ ln2_g,  const float* __restrict__ ln2_b,
    const float* __restrict__ b_gi,   const float* __restrict__ b_gm,
    const __bf16* __restrict__ wWin,  const __bf16* __restrict__ wWqkv,
    const __bf16* __restrict__ wWc,   const __bf16* __restrict__ wWgi,
    const __bf16* __restrict__ wWgm,  const float* __restrict__ bc,
    float* __restrict__ out0, float* __restrict__ out1)
{
  __shared__ __align__(16) char smem[LDSSZ];
  const int tid  = threadIdx.x;
  const int lane = tid & 63;
  const int wv   = tid >> 6;
  const int l15  = lane & 15;
  const int lg   = lane >> 4;
  const int s    = blockIdx.x*4 + wv;
  const float QSC = 0.1020620726159658f;   // 96^-0.5

  char* SL = smem + wv*SLAB;
  char* MP = SL;
  char* GI = SL + 2304;
  char* XT = SL + 3072;
  char* QK = SL + 3328;

  // ---- P0a: zero the only scratch spans read before first write ----
  // MP rows 9..11 (A-tile garbage rows) + QK first 768B (MP-tile rows 13..15).
  if (lane < 48){
    *(f32x4*)(SL + 2304 + lane*16) = (f32x4){0.f,0.f,0.f,0.f};
    *(f32x4*)(SL + 3328 + lane*16) = (f32x4){0.f,0.f,0.f,0.f};
  }

  // ---- P0b: stage input row (XT, linear) + memory rows (MP bf16, swz) ----
  if (lane < 32){
    f32x4 v = *(const f32x4*)(inputs + (size_t)s*128 + lane*4);
    bf16x4 h; h[0]=(__bf16)v[0]; h[1]=(__bf16)v[1]; h[2]=(__bf16)v[2]; h[3]=(__bf16)v[3];
    *(bf16x4*)(XT + lane*8) = h;
  }
#pragma unroll
  for (int it=0; it<4; ++it){
    int e0 = it*256 + lane*4, row = e0>>7, col = e0&127;
    f32x4 v = *(const f32x4*)(memory + (size_t)s*1024 + e0);
    bf16x4 h; h[0]=(__bf16)v[0]; h[1]=(__bf16)v[1]; h[2]=(__bf16)v[2]; h[3]=(__bf16)v[3];
    *(bf16x4*)swz(MP, row, 256, col*2) = h;
  }

  // ---- P1: x = inputs @ W_in + b_in  (broadcast A-row) ----
  {
    bf16x8 a[4];
#pragma unroll
    for (int k=0;k<4;k++) a[k] = *(const bf16x8*)(XT + k*64 + lg*16);  // all lanes same row
    gemmW<8>(wWin, a, l15, lg, [&](int nt, f32x4 acc){
      if (lg == 0){
        int c = nt*16 + l15;
        __bf16 h = (__bf16)(acc[0] + b_in[c]);
        *(__bf16*)swz(MP, 8, 256, c*2) = h;   // mp slot 8
        *(__bf16*)(XT + c*2) = h;             // x copy (for gi GEMM)
      }
    });
  }

  // ---- P2: qkv = mp @ W_qkv + b_qkv  (9 valid rows, N=384) ----
  {
    bf16x8 a[4];
#pragma unroll
    for (int k=0;k<4;k++) a[k] = *(const bf16x8*)swz(MP, l15, 256, k*64 + lg*16);
    gemmW<24>(wWqkv, a, l15, lg, [&](int nt, f32x4 acc){
      int c = nt*16 + l15;
      float bq = b_qkv[c];
#pragma unroll
      for (int r=0;r<4;r++){
        int row = 4*lg + r;
        if (row < 9) *(__bf16*)swz(QK, row, 768, c*2) = (__bf16)(acc[r] + bq);
      }
    });
  }

  // ---- P3: LN(qkv) in place + fold q-scale ----
  {
    auto ln384 = [&](int r, int j){
      float x[48]; float sm=0.f, sq=0.f;
#pragma unroll
      for (int t=0;t<6;t++){
        bf16x8 h = *(const bf16x8*)swz(QK, r, 768, j*96 + t*16);
#pragma unroll
        for (int e=0;e<8;e++){ float f=(float)h[e]; x[t*8+e]=f; sm+=f; sq+=f*f; }
      }
#pragma unroll
      for (int o=1;o<8;o<<=1){ sm += __shfl_xor(sm,o); sq += __shfl_xor(sq,o); }
      float mean = sm*(1.f/384.f), var = sq*(1.f/384.f)-mean*mean, rs = rsqrtf(var+1e-5f);
      int jodd = j & 1;
#pragma unroll
      for (int t=0;t<6;t++){
        int cb = j*48 + t*8;
        f32x4 g0 = *(const f32x4*)(lnq_g+cb), g1 = *(const f32x4*)(lnq_g+cb+4);
        f32x4 e0 = *(const f32x4*)(lnq_b+cb), e1 = *(const f32x4*)(lnq_b+cb+4);
        bf16x8 h;
#pragma unroll
        for (int e=0;e<8;e++){
          float gg = (e<4) ? g0[e] : g1[e-4];
          float bb = (e<4) ? e0[e] : e1[e-4];
          float y = gg*(x[t*8+e]-mean)*rs + bb;
          if (!jodd && (t*8+e) < 32) y *= QSC;   // (c%96)<32
          h[e] = (__bf16)y;
        }
        *(bf16x8*)swz(QK, r, 768, j*96 + t*16) = h;
      }
    };
    ln384(lane>>3, lane&7);
    if (lane < 8) ln384(8, lane);
  }

  // ---- P4: attention. QK^T via 4 MFMA; P stored in dead q-slices; PV; out -> q-slices ----
  {
    const int arow = (l15 < 9) ? l15 : 8;   // clamp: never read beyond row 8
    f32x4 sc[4];
#pragma unroll
    for (int h=0;h<4;h++){
      bf16x8 qa = *(const bf16x8*)swz(QK, arow, 768, h*192 + lg*16);
      bf16x8 kb = *(const bf16x8*)swz(QK, arow, 768, h*192 + 64 + lg*16);
      sc[h] = __builtin_amdgcn_mfma_f32_16x16x32_bf16(qa, kb, (f32x4){0.f,0.f,0.f,0.f}, 0, 0, 0);
    }
#pragma unroll
    for (int h=0;h<4;h++){
#pragma unroll
      for (int r=0;r<4;r++){
        int row = 4*lg + r;                       // q index
        float v = (l15 < 9) ? sc[h][r] : -1e30f;  // mask duplicate/pad k
        float mx = v;
#pragma unroll
        for (int o=1;o<16;o<<=1) mx = fmaxf(mx, __shfl_xor(mx, o));
        float p = __expf(v - mx);
        float sm = p;
#pragma unroll
        for (int o=1;o<16;o<<=1) sm += __shfl_xor(sm, o);
        float pn = p / sm;
        if (row < 9) *(__bf16*)swz(QK, row, 768, h*192 + l15*2) = (__bf16)pn;  // P -> q-slice
      }
    }
    // PV: 144 tasks = (q 0..8) x (16 8-col chunks); per pass all P-reads precede out-writes
#pragma unroll
    for (int pass=0; pass<3; ++pass){
      int t = pass*64 + lane;
      if (t < 144){
        int q = t>>4, ch = t&15, h = ch>>2, d16 = (ch&3)*16;
        float o8[8] = {0.f,0.f,0.f,0.f,0.f,0.f,0.f,0.f};
#pragma unroll
        for (int k=0;k<9;k++){
          float p = (float)*(const __bf16*)swz(QK, q, 768, h*192 + k*2);
          bf16x8 v8 = *(const bf16x8*)swz(QK, k, 768, h*192 + 128 + d16);
#pragma unroll
          for (int e=0;e<8;e++) o8[e] += p*(float)v8[e];
        }
        bf16x8 ho;
#pragma unroll
        for (int e=0;e<8;e++) ho[e] = (__bf16)o8[e];
        *(bf16x8*)swz(QK, q, 768, h*192 + d16) = ho;
      }
    }
  }

  // ---- P5: mem = LN(mp + out) -> MP in place ----
  {
    auto ln1 = [&](int r, int j){
      bf16x8 m0 = *(const bf16x8*)swz(MP, r, 256, j*32);
      bf16x8 m1 = *(const bf16x8*)swz(MP, r, 256, j*32 + 16);
      int ob = (j>>1)*192 + (j&1)*32;
      bf16x8 o0 = *(const bf16x8*)swz(QK, r, 768, ob);
      bf16x8 o1 = *(const bf16x8*)swz(QK, r, 768, ob + 16);
      float tv[16]; float sm=0.f, sq=0.f;
#pragma unroll
      for (int e=0;e<8;e++){
        float a = (float)m0[e] + (float)o0[e]; tv[e]   = a; sm += a; sq += a*a;
        float b = (float)m1[e] + (float)o1[e]; tv[8+e] = b; sm += b; sq += b*b;
      }
#pragma unroll
      for (int o=1;o<8;o<<=1){ sm += __shfl_xor(sm,o); sq += __shfl_xor(sq,o); }
      float mean = sm*(1.f/128.f), var = sq*(1.f/128.f)-mean*mean, rs = rsqrtf(var+1e-5f);
      int cb = j*16;
      f32x4 g0 = *(const f32x4*)(ln1_g+cb),   g1 = *(const f32x4*)(ln1_g+cb+4);
      f32x4 g2 = *(const f32x4*)(ln1_g+cb+8), g3 = *(const f32x4*)(ln1_g+cb+12);
      f32x4 e0 = *(const f32x4*)(ln1_b+cb),   e1 = *(const f32x4*)(ln1_b+cb+4);
      f32x4 e2 = *(const f32x4*)(ln1_b+cb+8), e3 = *(const f32x4*)(ln1_b+cb+12);
      bf16x8 h0, h1;
#pragma unroll
      for (int e=0;e<8;e++){
        float ga = (e<4)?g0[e]:g1[e-4], ba = (e<4)?e0[e]:e1[e-4];
        float gb = (e<4)?g2[e]:g3[e-4], bb = (e<4)?e2[e]:e3[e-4];
        h0[e] = (__bf16)(ga*(tv[e]  -mean)*rs + ba);
        h1[e] = (__bf16)(gb*(tv[8+e]-mean)*rs + bb);
      }
      *(bf16x8*)swz(MP, r, 256, j*32)      = h0;
      *(bf16x8*)swz(MP, r, 256, j*32 + 16) = h1;
    };
    ln1(lane>>3, lane&7);
    if (lane < 8) ln1(8, lane);
  }

  // ---- P6: mlp = mem @ (W_m1 W_m2) + bc -> QK f32 [9][512] swz ----
  {
    bf16x8 a[4];
#pragma unroll
    for (int k=0;k<4;k++) a[k] = *(const bf16x8*)swz(MP, l15, 256, k*64 + lg*16);
    gemmW<8>(wWc, a, l15, lg, [&](int nt, f32x4 acc){
      int c = nt*16 + l15;
      float bcv = bc[c];
#pragma unroll
      for (int r=0;r<4;r++){
        int row = 4*lg + r;
        if (row < 9) *(float*)swz(QK, row, 512, c*4) = acc[r] + bcv;
      }
    });
  }

  // ---- P7: mem2 = LN(mlp + mem), rows 0..7 -> QK+4608 bf16 [8][256] swz ----
  {
    int r = lane>>3, j = lane&7;
    f32x4 p0 = *(const f32x4*)swz(QK, r, 512, j*64);
    f32x4 p1 = *(const f32x4*)swz(QK, r, 512, j*64 + 16);
    f32x4 p2 = *(const f32x4*)swz(QK, r, 512, j*64 + 32);
    f32x4 p3 = *(const f32x4*)swz(QK, r, 512, j*64 + 48);
    bf16x8 m0 = *(const bf16x8*)swz(MP, r, 256, j*32);
    bf16x8 m1 = *(const bf16x8*)swz(MP, r, 256, j*32 + 16);
    float tv[16]; float sm=0.f, sq=0.f;
#pragma unroll
    for (int e=0;e<8;e++){
      float a = ((e<4)?p0[e]:p1[e-4]) + (float)m0[e]; tv[e]   = a; sm += a; sq += a*a;
      float b = ((e<4)?p2[e]:p3[e-4]) + (float)m1[e]; tv[8+e] = b; sm += b; sq += b*b;
    }
#pragma unroll
    for (int o=1;o<8;o<<=1){ sm += __shfl_xor(sm,o); sq += __shfl_xor(sq,o); }
    float mean = sm*(1.f/128.f), var = sq*(1.f/128.f)-mean*mean, rs = rsqrtf(var+1e-5f);
    int cb = j*16;
    f32x4 g0 = *(const f32x4*)(ln2_g+cb),   g1 = *(const f32x4*)(ln2_g+cb+4);
    f32x4 g2 = *(const f32x4*)(ln2_g+cb+8), g3 = *(const f32x4*)(ln2_g+cb+12);
    f32x4 e0 = *(const f32x4*)(ln2_b+cb),   e1 = *(const f32x4*)(ln2_b+cb+4);
    f32x4 e2 = *(const f32x4*)(ln2_b+cb+8), e3 = *(const f32x4*)(ln2_b+cb+12);
    bf16x8 h0, h1;
#pragma unroll
    for (int e=0;e<8;e++){
      float ga = (e<4)?g0[e]:g1[e-4], ba = (e<4)?e0[e]:e1[e-4];
      float gb = (e<4)?g2[e]:g3[e-4], bb = (e<4)?e2[e]:e3[e-4];
      h0[e] = (__bf16)(ga*(tv[e]  -mean)*rs + ba);
      h1[e] = (__bf16)(gb*(tv[8+e]-mean)*rs + bb);
    }
    *(bf16x8*)swz(QK + 4608, r, 256, j*32)      = h0;
    *(bf16x8*)swz(QK + 4608, r, 256, j*32 + 16) = h1;
  }

  // ---- P8: gi = x @ W_gi + b_gi -> GI; memory -> tanh bf16 (MP) + f32 stash (memf=QK) ----
  {
    bf16x8 a[4];
#pragma unroll
    for (int k=0;k<4;k++) a[k] = *(const bf16x8*)(XT + k*64 + lg*16);  // broadcast x row
    gemmW<16>(wWgi, a, l15, lg, [&](int nt, f32x4 acc){
      if (lg == 0){
        int c = nt*16 + l15;
        *(float*)(GI + c*4) = acc[0] + b_gi[c];   // clobbers XT tail only after a[] loaded
      }
    });
#pragma unroll
    for (int it=0; it<4; ++it){
      int e0 = it*256 + lane*4, row = e0>>7, col = e0&127;
      f32x4 v = *(const f32x4*)(memory + (size_t)s*1024 + e0);
      *(f32x4*)swz(QK, row, 512, col*4) = v;                 // memf f32 stash (mlp dead)
      bf16x4 h; h[0]=(__bf16)tanhf_(v[0]); h[1]=(__bf16)tanhf_(v[1]);
                h[2]=(__bf16)tanhf_(v[2]); h[3]=(__bf16)tanhf_(v[3]);
      *(bf16x4*)swz(MP, row, 256, col*2) = h;
    }
  }

  // ---- P9: gm = tanh(memory) @ W_gm + b_gm; gates; nm staged in LDS; coalesced dump ----
  {
    bf16x8 a[4];
#pragma unroll
    for (int k=0;k<4;k++) a[k] = *(const bf16x8*)swz(MP, l15, 256, k*64 + lg*16);
    f32x4 accI[8];
    gemmW<8>(wWgm, a, l15, lg, [&](int nt, f32x4 acc){ accI[nt] = acc; });
    gemmW<8>(wWgm + 16384, a, l15, lg, [&](int nt, f32x4 accF){
      int c = nt*16 + l15;
      float giv = *(const float*)(GI + c*4);
      float gfv = *(const float*)(GI + (128+c)*4);
      float bgi = b_gm[c], bgf = b_gm[128+c];
#pragma unroll
      for (int r=0;r<4;r++){
        int row = 4*lg + r;            // slot j
        if (row < 8){
          float g_i = accI[nt][r] + bgi + giv;
          float g_f = accF[r]     + bgf + gfv + 1.0f;
          float ig = sigmoidf_(g_i), fg = sigmoidf_(g_f);
          float m2 = (float)*(const __bf16*)swz(QK + 4608, row, 256, c*2);
          float mo = *(const float*)swz(QK, row, 512, c*4);
          *(float*)swz(QK, row, 512, c*4) = ig*tanhf_(m2) + fg*mo;  // nm in-place
        }
      }
    });
    // coalesced dump: 4 x 1KB contiguous stores per output buffer
    float* o0 = out0 + (size_t)s*1024;
    float* o1 = out1 + (size_t)s*1024;
#pragma unroll
    for (int i=0; i<4; ++i){
      int lb = i*1024 + lane*16;
      f32x4 v = *(const f32x4*)swz(QK, lb>>9, 512, lb & 511);
      *(f32x4*)(o0 + i*256 + lane*4) = v;
      *(f32x4*)(o1 + i*256 + lane*4) = v;
    }
  }
}

// ---------------- launch ----------------
extern "C" void kernel_launch(void* const* d_in, const int* in_sizes, int n_in,
                              void* d_out, int out_size, void* d_ws, size_t ws_size,
                              hipStream_t stream) {
  const float* inputs = (const float*)d_in[0];
  const float* memory = (const float*)d_in[1];
  const float* W_in   = (const float*)d_in[2];
  const float* b_in   = (const float*)d_in[3];
  const float* W_qkv  = (const float*)d_in[4];
  const float* b_qkv  = (const float*)d_in[5];
  const float* lnq_g  = (const float*)d_in[6];
  const float* lnq_b  = (const float*)d_in[7];
  const float* ln1_g  = (const float*)d_in[8];
  const float* ln1_b  = (const float*)d_in[9];
  const float* W_m1   = (const float*)d_in[10];
  const float* b_m1   = (const float*)d_in[11];
  const float* W_m2   = (const float*)d_in[12];
  const float* b_m2   = (const float*)d_in[13];
  const float* ln2_g  = (const float*)d_in[14];
  const float* ln2_b  = (const float*)d_in[15];
  const float* W_gi   = (const float*)d_in[16];
  const float* b_gi   = (const float*)d_in[17];
  const float* W_gm   = (const float*)d_in[18];
  const float* b_gm   = (const float*)d_in[19];

  __bf16* ws16 = (__bf16*)d_ws;
  float* bcp = (float*)((char*)d_ws + WS_BC);
  const __bf16* wWin  = (const __bf16*)((char*)d_ws + WS_WIN);
  const __bf16* wWqkv = (const __bf16*)((char*)d_ws + WS_WQKV);
  const __bf16* wWc   = (const __bf16*)((char*)d_ws + WS_WC);
  const __bf16* wWgi  = (const __bf16*)((char*)d_ws + WS_WGI);
  const __bf16* wWgm  = (const __bf16*)((char*)d_ws + WS_WGM);

  float* out0 = (float*)d_out;
  float* out1 = out0 + (size_t)BATCH*1024;

  prep_kernel<<<dim3(256), dim3(256), 0, stream>>>(
      W_in, W_qkv, W_m1, W_m2, b_m1, b_m2, W_gi, W_gm, ws16, bcp);

  rmc_kernel<<<dim3(NBLK), dim3(256), 0, stream>>>(
      inputs, memory, b_in, b_qkv, lnq_g, lnq_b, ln1_g, ln1_b, ln2_g, ln2_b,
      b_gi, b_gm, wWin, wWqkv, wWc, wWgi, wWgm, bcp, out0, out1);
}

// Round 6
// 1349.490 us; speedup vs baseline: 1.0799x; 1.0790x over previous
//
#include <hip/hip_runtime.h>
#include <cstdint>
#include <cstddef>

// ---------------- constants ----------------
#define BATCH   32768
#define NBLK    (BATCH/4)    // 8192 blocks, 4 waves/block, 1 sample/wave

// d_ws byte offsets (bf16 transposed weights + collapsed MLP)
#define WS_WIN   0            // [128][128] bf16  WinT[n][k] = W_in[k][n]
#define WS_WQKV  32768        // [384][128] bf16
#define WS_WC    131072       // [128][128] bf16  (W_m1 @ W_m2)^T
#define WS_WGI   163840       // [256][128] bf16
#define WS_WGM   229376       // [256][128] bf16
#define WS_BC    294912       // [128] f32        b_m1 @ W_m2 + b_m2

// per-wave LDS slab: 10240 B -> block 40960 B -> EXACTLY 4 blocks/CU (160 KiB).
#define SLAB   10240
#define LDSSZ  40960

// lockstep barrier: NO data crosses waves (slabs private); this only caps wave drift
// so the 4 waves' identical weight streams share L1. Raw s_barrier (no vmcnt drain).
#define PB() __builtin_amdgcn_s_barrier()

typedef __bf16 bf16x8 __attribute__((ext_vector_type(8)));
typedef __bf16 bf16x4 __attribute__((ext_vector_type(4)));
typedef float  f32x4  __attribute__((ext_vector_type(4)));

__device__ __forceinline__ float sigmoidf_(float x){ return 1.f/(1.f+__expf(-x)); }
__device__ __forceinline__ float tanhf_(float x){ float e = __expf(2.f*x); return 1.f - 2.f/(e+1.f); }

// XOR bank swizzle: permute 16B blocks within each row by row&7.
__device__ __forceinline__ char* swz(char* base, int row, int stride, int colb){
  return base + row*stride + (colb ^ ((row & 7) << 4));
}

// Depth-1 software-pipelined weight GEMM: B-frags for nt+1 load while nt's MFMAs run.
template<int NT, typename FC>
__device__ __forceinline__ void gemmW(const __bf16* __restrict__ W,
                                      const bf16x8 (&a)[4], const int l15, const int lg,
                                      FC consume){
  bf16x8 b0[4], b1[4];
#pragma unroll
  for (int k=0;k<4;k++) b0[k] = *(const bf16x8*)(W + l15*128 + k*32 + lg*8);
#pragma unroll
  for (int nt=0; nt<NT; ++nt){
    if (nt+1 < NT){
      const __bf16* Wn = W + (nt+1)*16*128;
      if ((nt&1)==0){
#pragma unroll
        for (int k=0;k<4;k++) b1[k] = *(const bf16x8*)(Wn + l15*128 + k*32 + lg*8);
      } else {
#pragma unroll
        for (int k=0;k<4;k++) b0[k] = *(const bf16x8*)(Wn + l15*128 + k*32 + lg*8);
      }
    }
    f32x4 acc = {0.f,0.f,0.f,0.f};
    if ((nt&1)==0){
#pragma unroll
      for (int k=0;k<4;k++) acc = __builtin_amdgcn_mfma_f32_16x16x32_bf16(a[k], b0[k], acc, 0,0,0);
    } else {
#pragma unroll
      for (int k=0;k<4;k++) acc = __builtin_amdgcn_mfma_f32_16x16x32_bf16(a[k], b1[k], acc, 0,0,0);
    }
    consume(nt, acc);
  }
}

// ---------------- weight prep: f32 -> bf16 transposed, W_m1@W_m2 collapsed ----------------
__global__ __launch_bounds__(256) void prep_kernel(
    const float* __restrict__ W_in,  const float* __restrict__ W_qkv,
    const float* __restrict__ W_m1,  const float* __restrict__ W_m2,
    const float* __restrict__ b_m1,  const float* __restrict__ b_m2,
    const float* __restrict__ W_gi,  const float* __restrict__ W_gm,
    __bf16* __restrict__ ws, float* __restrict__ bc)
{
  int gt = blockIdx.x*256 + threadIdx.x;
  int NT = gridDim.x*256;
  for (int i = gt; i < 128*128; i += NT){ int n=i>>7, k=i&127; ws[(WS_WIN >>1)+i] = (__bf16)W_in [k*128+n]; }
  for (int i = gt; i < 384*128; i += NT){ int n=i>>7, k=i&127; ws[(WS_WQKV>>1)+i] = (__bf16)W_qkv[k*384+n]; }
  for (int i = gt; i < 256*128; i += NT){ int n=i>>7, k=i&127; ws[(WS_WGI >>1)+i] = (__bf16)W_gi [k*256+n]; }
  for (int i = gt; i < 256*128; i += NT){ int n=i>>7, k=i&127; ws[(WS_WGM >>1)+i] = (__bf16)W_gm [k*256+n]; }
  for (int i = gt; i < 128*128; i += NT){
    int n=i>>7, k=i&127;
    float s = 0.f;
    for (int j=0;j<128;j++) s += W_m1[k*128+j]*W_m2[j*128+n];
    ws[(WS_WC>>1)+i] = (__bf16)s;
  }
  for (int i = gt; i < 128; i += NT){
    float s = b_m2[i];
    for (int j=0;j<128;j++) s += b_m1[j]*W_m2[j*128+i];
    bc[i] = s;
  }
}

// ---------------- fused main kernel: one WAVE owns one sample ----------------
// Slab layout / determinism invariants: see R4 notes (unchanged).
//  MP [0,3328)     : bf16 13 rows x 256B swz; rows 9..12 scratch (GI @+2304, XT @+3072).
//  QK [3328,10240) : qkv bf16 [9][768] swz; P + attn-out in dead q-slices; later
//                    mlp f32 [9][512]; mem2 bf16 [8][256] @+4608; memf f32 / nm [8][512].
__global__ __launch_bounds__(256) __attribute__((amdgpu_waves_per_eu(4,4)))
void rmc_kernel(
    const float* __restrict__ inputs, const float* __restrict__ memory,
    const float* __restrict__ b_in,   const float* __restrict__ b_qkv,
    const float* __restrict__ lnq_g,  const float* __restrict__ lnq_b,
    const float* __restrict__ ln1_g,  const float* __restrict__ ln1_b,
    const float* __restrict__ ln2_g,  const float* __restrict__ ln2_b,
    const float* __restrict__ b_gi,   const float* __restrict__ b_gm,
    const __bf16* __restrict__ wWin,  const __bf16* __restrict__ wWqkv,
    const __bf16* __restrict__ wWc,   const __bf16* __restrict__ wWgi,
    const __bf16* __restrict__ wWgm,  const float* __restrict__ bc,
    float* __restrict__ out0, float* __restrict__ out1)
{
  __shared__ __align__(16) char smem[LDSSZ];
  const int tid  = threadIdx.x;
  const int lane = tid & 63;
  const int wv   = tid >> 6;
  const int l15  = lane & 15;
  const int lg   = lane >> 4;
  const int s    = blockIdx.x*4 + wv;
  const float QSC = 0.1020620726159658f;   // 96^-0.5

  char* SL = smem + wv*SLAB;
  char* MP = SL;
  char* GI = SL + 2304;
  char* XT = SL + 3072;
  char* QK = SL + 3328;

  // ---- P0a: zero the only scratch spans read before first write ----
  if (lane < 48){
    *(f32x4*)(SL + 2304 + lane*16) = (f32x4){0.f,0.f,0.f,0.f};
    *(f32x4*)(SL + 3328 + lane*16) = (f32x4){0.f,0.f,0.f,0.f};
  }

  // ---- P0b: stage input row (XT, linear) + memory rows (MP bf16, swz) ----
  if (lane < 32){
    f32x4 v = *(const f32x4*)(inputs + (size_t)s*128 + lane*4);
    bf16x4 h; h[0]=(__bf16)v[0]; h[1]=(__bf16)v[1]; h[2]=(__bf16)v[2]; h[3]=(__bf16)v[3];
    *(bf16x4*)(XT + lane*8) = h;
  }
#pragma unroll
  for (int it=0; it<4; ++it){
    int e0 = it*256 + lane*4, row = e0>>7, col = e0&127;
    f32x4 v = *(const f32x4*)(memory + (size_t)s*1024 + e0);
    bf16x4 h; h[0]=(__bf16)v[0]; h[1]=(__bf16)v[1]; h[2]=(__bf16)v[2]; h[3]=(__bf16)v[3];
    *(bf16x4*)swz(MP, row, 256, col*2) = h;
  }
  PB();

  // ---- P1: x = inputs @ W_in + b_in  (broadcast A-row) ----
  {
    bf16x8 a[4];
#pragma unroll
    for (int k=0;k<4;k++) a[k] = *(const bf16x8*)(XT + k*64 + lg*16);  // all lanes same row
    gemmW<8>(wWin, a, l15, lg, [&](int nt, f32x4 acc){
      if (lg == 0){
        int c = nt*16 + l15;
        __bf16 h = (__bf16)(acc[0] + b_in[c]);
        *(__bf16*)swz(MP, 8, 256, c*2) = h;   // mp slot 8
        *(__bf16*)(XT + c*2) = h;             // x copy (for gi GEMM)
      }
    });
  }
  PB();

  // ---- P2: qkv = mp @ W_qkv + b_qkv  (9 valid rows, N=384) ----
  {
    bf16x8 a[4];
#pragma unroll
    for (int k=0;k<4;k++) a[k] = *(const bf16x8*)swz(MP, l15, 256, k*64 + lg*16);
    gemmW<24>(wWqkv, a, l15, lg, [&](int nt, f32x4 acc){
      int c = nt*16 + l15;
      float bq = b_qkv[c];
#pragma unroll
      for (int r=0;r<4;r++){
        int row = 4*lg + r;
        if (row < 9) *(__bf16*)swz(QK, row, 768, c*2) = (__bf16)(acc[r] + bq);
      }
    });
  }
  PB();

  // ---- P3: LN(qkv) in place + fold q-scale (two-pass: no x[48] live range) ----
  {
    auto ln384 = [&](int r, int j){
      float sm=0.f, sq=0.f;
#pragma unroll
      for (int t=0;t<6;t++){
        bf16x8 h = *(const bf16x8*)swz(QK, r, 768, j*96 + t*16);
#pragma unroll
        for (int e=0;e<8;e++){ float f=(float)h[e]; sm+=f; sq+=f*f; }
      }
#pragma unroll
      for (int o=1;o<8;o<<=1){ sm += __shfl_xor(sm,o); sq += __shfl_xor(sq,o); }
      float mean = sm*(1.f/384.f), var = sq*(1.f/384.f)-mean*mean, rs = rsqrtf(var+1e-5f);
      int jodd = j & 1;
#pragma unroll
      for (int t=0;t<6;t++){
        bf16x8 h = *(const bf16x8*)swz(QK, r, 768, j*96 + t*16);
        int cb = j*48 + t*8;
        f32x4 g0 = *(const f32x4*)(lnq_g+cb), g1 = *(const f32x4*)(lnq_g+cb+4);
        f32x4 e0 = *(const f32x4*)(lnq_b+cb), e1 = *(const f32x4*)(lnq_b+cb+4);
        bf16x8 ho;
#pragma unroll
        for (int e=0;e<8;e++){
          float gg = (e<4) ? g0[e] : g1[e-4];
          float bb = (e<4) ? e0[e] : e1[e-4];
          float y = gg*((float)h[e]-mean)*rs + bb;
          if (!jodd && (t*8+e) < 32) y *= QSC;   // (c%96)<32
          ho[e] = (__bf16)y;
        }
        *(bf16x8*)swz(QK, r, 768, j*96 + t*16) = ho;
      }
    };
    ln384(lane>>3, lane&7);
    if (lane < 8) ln384(8, lane);
  }
  PB();

  // ---- P4: attention. QK^T via 4 MFMA; P in dead q-slices; PV; out -> q-slices ----
  {
    const int arow = (l15 < 9) ? l15 : 8;   // clamp: never read beyond row 8
    f32x4 sc[4];
#pragma unroll
    for (int h=0;h<4;h++){
      bf16x8 qa = *(const bf16x8*)swz(QK, arow, 768, h*192 + lg*16);
      bf16x8 kb = *(const bf16x8*)swz(QK, arow, 768, h*192 + 64 + lg*16);
      sc[h] = __builtin_amdgcn_mfma_f32_16x16x32_bf16(qa, kb, (f32x4){0.f,0.f,0.f,0.f}, 0, 0, 0);
    }
#pragma unroll
    for (int h=0;h<4;h++){
#pragma unroll
      for (int r=0;r<4;r++){
        int row = 4*lg + r;                       // q index
        float v = (l15 < 9) ? sc[h][r] : -1e30f;  // mask duplicate/pad k
        float mx = v;
#pragma unroll
        for (int o=1;o<16;o<<=1) mx = fmaxf(mx, __shfl_xor(mx, o));
        float p = __expf(v - mx);
        float sm = p;
#pragma unroll
        for (int o=1;o<16;o<<=1) sm += __shfl_xor(sm, o);
        float pn = p / sm;
        if (row < 9) *(__bf16*)swz(QK, row, 768, h*192 + l15*2) = (__bf16)pn;  // P -> q-slice
      }
    }
#pragma unroll
    for (int pass=0; pass<3; ++pass){
      int t = pass*64 + lane;
      if (t < 144){
        int q = t>>4, ch = t&15, h = ch>>2, d16 = (ch&3)*16;
        float o8[8] = {0.f,0.f,0.f,0.f,0.f,0.f,0.f,0.f};
#pragma unroll
        for (int k=0;k<9;k++){
          float p = (float)*(const __bf16*)swz(QK, q, 768, h*192 + k*2);
          bf16x8 v8 = *(const bf16x8*)swz(QK, k, 768, h*192 + 128 + d16);
#pragma unroll
          for (int e=0;e<8;e++) o8[e] += p*(float)v8[e];
        }
        bf16x8 ho;
#pragma unroll
        for (int e=0;e<8;e++) ho[e] = (__bf16)o8[e];
        *(bf16x8*)swz(QK, q, 768, h*192 + d16) = ho;
      }
    }
  }
  PB();

  // ---- P5: mem = LN(mp + out) -> MP in place ----
  {
    auto ln1 = [&](int r, int j){
      bf16x8 m0 = *(const bf16x8*)swz(MP, r, 256, j*32);
      bf16x8 m1 = *(const bf16x8*)swz(MP, r, 256, j*32 + 16);
      int ob = (j>>1)*192 + (j&1)*32;
      bf16x8 o0 = *(const bf16x8*)swz(QK, r, 768, ob);
      bf16x8 o1 = *(const bf16x8*)swz(QK, r, 768, ob + 16);
      float tv[16]; float sm=0.f, sq=0.f;
#pragma unroll
      for (int e=0;e<8;e++){
        float a = (float)m0[e] + (float)o0[e]; tv[e]   = a; sm += a; sq += a*a;
        float b = (float)m1[e] + (float)o1[e]; tv[8+e] = b; sm += b; sq += b*b;
      }
#pragma unroll
      for (int o=1;o<8;o<<=1){ sm += __shfl_xor(sm,o); sq += __shfl_xor(sq,o); }
      float mean = sm*(1.f/128.f), var = sq*(1.f/128.f)-mean*mean, rs = rsqrtf(var+1e-5f);
      int cb = j*16;
      f32x4 g0 = *(const f32x4*)(ln1_g+cb),   g1 = *(const f32x4*)(ln1_g+cb+4);
      f32x4 g2 = *(const f32x4*)(ln1_g+cb+8), g3 = *(const f32x4*)(ln1_g+cb+12);
      f32x4 e0 = *(const f32x4*)(ln1_b+cb),   e1 = *(const f32x4*)(ln1_b+cb+4);
      f32x4 e2 = *(const f32x4*)(ln1_b+cb+8), e3 = *(const f32x4*)(ln1_b+cb+12);
      bf16x8 h0, h1;
#pragma unroll
      for (int e=0;e<8;e++){
        float ga = (e<4)?g0[e]:g1[e-4], ba = (e<4)?e0[e]:e1[e-4];
        float gb = (e<4)?g2[e]:g3[e-4], bb = (e<4)?e2[e]:e3[e-4];
        h0[e] = (__bf16)(ga*(tv[e]  -mean)*rs + ba);
        h1[e] = (__bf16)(gb*(tv[8+e]-mean)*rs + bb);
      }
      *(bf16x8*)swz(MP, r, 256, j*32)      = h0;
      *(bf16x8*)swz(MP, r, 256, j*32 + 16) = h1;
    };
    ln1(lane>>3, lane&7);
    if (lane < 8) ln1(8, lane);
  }
  PB();

  // ---- P6: mlp = mem @ (W_m1 W_m2) + bc -> QK f32 [9][512] swz ----
  {
    bf16x8 a[4];
#pragma unroll
    for (int k=0;k<4;k++) a[k] = *(const bf16x8*)swz(MP, l15, 256, k*64 + lg*16);
    gemmW<8>(wWc, a, l15, lg, [&](int nt, f32x4 acc){
      int c = nt*16 + l15;
      float bcv = bc[c];
#pragma unroll
      for (int r=0;r<4;r++){
        int row = 4*lg + r;
        if (row < 9) *(float*)swz(QK, row, 512, c*4) = acc[r] + bcv;
      }
    });
  }
  PB();

  // ---- P7: mem2 = LN(mlp + mem), rows 0..7 -> QK+4608 bf16 [8][256] swz ----
  {
    int r = lane>>3, j = lane&7;
    f32x4 p0 = *(const f32x4*)swz(QK, r, 512, j*64);
    f32x4 p1 = *(const f32x4*)swz(QK, r, 512, j*64 + 16);
    f32x4 p2 = *(const f32x4*)swz(QK, r, 512, j*64 + 32);
    f32x4 p3 = *(const f32x4*)swz(QK, r, 512, j*64 + 48);
    bf16x8 m0 = *(const bf16x8*)swz(MP, r, 256, j*32);
    bf16x8 m1 = *(const bf16x8*)swz(MP, r, 256, j*32 + 16);
    float tv[16]; float sm=0.f, sq=0.f;
#pragma unroll
    for (int e=0;e<8;e++){
      float a = ((e<4)?p0[e]:p1[e-4]) + (float)m0[e]; tv[e]   = a; sm += a; sq += a*a;
      float b = ((e<4)?p2[e]:p3[e-4]) + (float)m1[e]; tv[8+e] = b; sm += b; sq += b*b;
    }
#pragma unroll
    for (int o=1;o<8;o<<=1){ sm += __shfl_xor(sm,o); sq += __shfl_xor(sq,o); }
    float mean = sm*(1.f/128.f), var = sq*(1.f/128.f)-mean*mean, rs = rsqrtf(var+1e-5f);
    int cb = j*16;
    f32x4 g0 = *(const f32x4*)(ln2_g+cb),   g1 = *(const f32x4*)(ln2_g+cb+4);
    f32x4 g2 = *(const f32x4*)(ln2_g+cb+8), g3 = *(const f32x4*)(ln2_g+cb+12);
    f32x4 e0 = *(const f32x4*)(ln2_b+cb),   e1 = *(const f32x4*)(ln2_b+cb+4);
    f32x4 e2 = *(const f32x4*)(ln2_b+cb+8), e3 = *(const f32x4*)(ln2_b+cb+12);
    bf16x8 h0, h1;
#pragma unroll
    for (int e=0;e<8;e++){
      float ga = (e<4)?g0[e]:g1[e-4], ba = (e<4)?e0[e]:e1[e-4];
      float gb = (e<4)?g2[e]:g3[e-4], bb = (e<4)?e2[e]:e3[e-4];
      h0[e] = (__bf16)(ga*(tv[e]  -mean)*rs + ba);
      h1[e] = (__bf16)(gb*(tv[8+e]-mean)*rs + bb);
    }
    *(bf16x8*)swz(QK + 4608, r, 256, j*32)      = h0;
    *(bf16x8*)swz(QK + 4608, r, 256, j*32 + 16) = h1;
  }
  PB();

  // ---- P8: gi = x @ W_gi + b_gi -> GI; memory -> tanh bf16 (MP) + f32 stash (QK) ----
  {
    bf16x8 a[4];
#pragma unroll
    for (int k=0;k<4;k++) a[k] = *(const bf16x8*)(XT + k*64 + lg*16);  // broadcast x row
    gemmW<16>(wWgi, a, l15, lg, [&](int nt, f32x4 acc){
      if (lg == 0){
        int c = nt*16 + l15;
        *(float*)(GI + c*4) = acc[0] + b_gi[c];
      }
    });
#pragma unroll
    for (int it=0; it<4; ++it){
      int e0 = it*256 + lane*4, row = e0>>7, col = e0&127;
      f32x4 v = *(const f32x4*)(memory + (size_t)s*1024 + e0);
      *(f32x4*)swz(QK, row, 512, col*4) = v;                 // memf f32 stash
      bf16x4 h; h[0]=(__bf16)tanhf_(v[0]); h[1]=(__bf16)tanhf_(v[1]);
                h[2]=(__bf16)tanhf_(v[2]); h[3]=(__bf16)tanhf_(v[3]);
      *(bf16x4*)swz(MP, row, 256, col*2) = h;
    }
  }
  PB();

  // ---- P9: gm = tanh(memory) @ W_gm + b_gm; gates; nm in LDS; coalesced dump ----
  {
    bf16x8 a[4];
#pragma unroll
    for (int k=0;k<4;k++) a[k] = *(const bf16x8*)swz(MP, l15, 256, k*64 + lg*16);
    f32x4 accI[8];
    gemmW<8>(wWgm, a, l15, lg, [&](int nt, f32x4 acc){ accI[nt] = acc; });
    gemmW<8>(wWgm + 16384, a, l15, lg, [&](int nt, f32x4 accF){
      int c = nt*16 + l15;
      float giv = *(const float*)(GI + c*4);
      float gfv = *(const float*)(GI + (128+c)*4);
      float bgi = b_gm[c], bgf = b_gm[128+c];
#pragma unroll
      for (int r=0;r<4;r++){
        int row = 4*lg + r;            // slot j
        if (row < 8){
          float g_i = accI[nt][r] + bgi + giv;
          float g_f = accF[r]     + bgf + gfv + 1.0f;
          float ig = sigmoidf_(g_i), fg = sigmoidf_(g_f);
          float m2 = (float)*(const __bf16*)swz(QK + 4608, row, 256, c*2);
          float mo = *(const float*)swz(QK, row, 512, c*4);
          *(float*)swz(QK, row, 512, c*4) = ig*tanhf_(m2) + fg*mo;  // nm in-place
        }
      }
    });
    // coalesced dump: 4 x 1KB contiguous stores per output buffer
    float* o0 = out0 + (size_t)s*1024;
    float* o1 = out1 + (size_t)s*1024;
#pragma unroll
    for (int i=0; i<4; ++i){
      int lb = i*1024 + lane*16;
      f32x4 v = *(const f32x4*)swz(QK, lb>>9, 512, lb & 511);
      *(f32x4*)(o0 + i*256 + lane*4) = v;
      *(f32x4*)(o1 + i*256 + lane*4) = v;
    }
  }
}

// ---------------- launch ----------------
extern "C" void kernel_launch(void* const* d_in, const int* in_sizes, int n_in,
                              void* d_out, int out_size, void* d_ws, size_t ws_size,
                              hipStream_t stream) {
  const float* inputs = (const float*)d_in[0];
  const float* memory = (const float*)d_in[1];
  const float* W_in   = (const float*)d_in[2];
  const float* b_in   = (const float*)d_in[3];
  const float* W_qkv  = (const float*)d_in[4];
  const float* b_qkv  = (const float*)d_in[5];
  const float* lnq_g  = (const float*)d_in[6];
  const float* lnq_b  = (const float*)d_in[7];
  const float* ln1_g  = (const float*)d_in[8];
  const float* ln1_b  = (const float*)d_in[9];
  const float* W_m1   = (const float*)d_in[10];
  const float* b_m1   = (const float*)d_in[11];
  const float* W_m2   = (const float*)d_in[12];
  const float* b_m2   = (const float*)d_in[13];
  const float* ln2_g  = (const float*)d_in[14];
  const float* ln2_b  = (const float*)d_in[15];
  const float* W_gi   = (const float*)d_in[16];
  const float* b_gi   = (const float*)d_in[17];
  const float* W_gm   = (const float*)d_in[18];
  const float* b_gm   = (const float*)d_in[19];

  __bf16* ws16 = (__bf16*)d_ws;
  float* bcp = (float*)((char*)d_ws + WS_BC);
  const __bf16* wWin  = (const __bf16*)((char*)d_ws + WS_WIN);
  const __bf16* wWqkv = (const __bf16*)((char*)d_ws + WS_WQKV);
  const __bf16* wWc   = (const __bf16*)((char*)d_ws + WS_WC);
  const __bf16* wWgi  = (const __bf16*)((char*)d_ws + WS_WGI);
  const __bf16* wWgm  = (const __bf16*)((char*)d_ws + WS_WGM);

  float* out0 = (float*)d_out;
  float* out1 = out0 + (size_t)BATCH*1024;

  prep_kernel<<<dim3(256), dim3(256), 0, stream>>>(
      W_in, W_qkv, W_m1, W_m2, b_m1, b_m2, W_gi, W_gm, ws16, bcp);

  rmc_kernel<<<dim3(NBLK), dim3(256), 0, stream>>>(
      inputs, memory, b_in, b_qkv, lnq_g, lnq_b, ln1_g, ln1_b, ln2_g, ln2_b,
      b_gi, b_gm, wWin, wWqkv, wWc, wWgi, wWgm, bcp, out0, out1);
}

// Round 9
// 1023.749 us; speedup vs baseline: 1.4236x; 1.3182x over previous
//
#include <hip/hip_runtime.h>
#include <cstdint>
#include <cstddef>

// ---------------- constants ----------------
#define BATCH   32768
#define BT      4            // samples per workgroup
#define S1      9            // SLOTS+1
#define RROWS   36           // BT*S1
#define NBLK    (BATCH/BT)   // 8192

// d_ws byte offsets (bf16 transposed weights + collapsed MLP)
#define WS_WIN   0            // [128][128] bf16  WinT[n][k] = W_in[k][n]
#define WS_WQKV  32768        // [384][128] bf16
#define WS_WC    131072       // [128][128] bf16  (W_m1 @ W_m2)^T
#define WS_WGI   163840       // [256][128] bf16
#define WS_WGM   229376       // [256][128] bf16
#define WS_BC    294912       // [128] f32        b_m1 @ W_m2 + b_m2

// LDS plan (37888 B total; 4 blocks/CU if VGPR<=128, else 3):
//  Q [0,27648)      qkv bf16 [36][768B] swz. attn-out overwrites dead q-slices (P4).
//                   Later: mlp f32 [36][512B] swz @0 (P6); mem2 bf16 [32][256B] swz @19456
//                   compact rows s*8+j (P7); gib f32 [4][1024B] swz @0 (P8, over dead mlp).
//  A [27648,36864)  amp bf16 [36][256B] swz: mp rows s*9+slot -> mem (P5 in place) ->
//                   tanh(memory) compact [32] rows (P8).
//  X [36864,37888)  x bf16 [4][256B] swz: staged inputs -> x (P1 in place).
// No zero padding anywhere: A-fragment row indices are CLAMPED (duplicate rows only
// affect C rows that are discarded by row guards).
#define A_OFF  27648
#define X_OFF  36864
#define MEM2   19456
#define LDSSZ  37888

typedef __bf16 bf16x8 __attribute__((ext_vector_type(8), may_alias));
typedef __bf16 bf16x4 __attribute__((ext_vector_type(4), may_alias));
typedef float  f32x4  __attribute__((ext_vector_type(4), may_alias));
typedef __bf16 bf16s  __attribute__((may_alias));
typedef float  f32s   __attribute__((may_alias));

__device__ __forceinline__ float sigmoidf_(float x){ return 1.f/(1.f+__expf(-x)); }
__device__ __forceinline__ float tanhf_(float x){ float e = __expf(2.f*x); return 1.f - 2.f/(e+1.f); }

// XOR bank swizzle: permute 16B blocks within each row by row&7 (T2 recipe).
__device__ __forceinline__ char* swz(char* base, int row, int stride, int colb){
  return base + row*stride + (colb ^ ((row & 7) << 4));
}

// ---------------- weight prep: f32 -> bf16 transposed, W_m1@W_m2 collapsed ----------------
__global__ __launch_bounds__(256) void prep_kernel(
    const float* __restrict__ W_in,  const float* __restrict__ W_qkv,
    const float* __restrict__ W_m1,  const float* __restrict__ W_m2,
    const float* __restrict__ b_m1,  const float* __restrict__ b_m2,
    const float* __restrict__ W_gi,  const float* __restrict__ W_gm,
    __bf16* __restrict__ ws, float* __restrict__ bc)
{
  int gt = blockIdx.x*256 + threadIdx.x;
  int NT = gridDim.x*256;
  for (int i = gt; i < 128*128; i += NT){ int n=i>>7, k=i&127; ws[(WS_WIN >>1)+i] = (__bf16)W_in [k*128+n]; }
  for (int i = gt; i < 384*128; i += NT){ int n=i>>7, k=i&127; ws[(WS_WQKV>>1)+i] = (__bf16)W_qkv[k*384+n]; }
  for (int i = gt; i < 256*128; i += NT){ int n=i>>7, k=i&127; ws[(WS_WGI >>1)+i] = (__bf16)W_gi [k*256+n]; }
  for (int i = gt; i < 256*128; i += NT){ int n=i>>7, k=i&127; ws[(WS_WGM >>1)+i] = (__bf16)W_gm [k*256+n]; }
  for (int i = gt; i < 128*128; i += NT){
    int n=i>>7, k=i&127;
    float s = 0.f;
    for (int j=0;j<128;j++) s += W_m1[k*128+j]*W_m2[j*128+n];
    ws[(WS_WC>>1)+i] = (__bf16)s;
  }
  for (int i = gt; i < 128; i += NT){
    float s = b_m2[i];
    for (int j=0;j<128;j++) s += b_m1[j]*W_m2[j*128+i];
    bc[i] = s;
  }
}

// ---------------- fused main kernel (R2 block-cooperative architecture) ----------------
__global__ __launch_bounds__(256) void rmc_kernel(
    const float* __restrict__ inputs, const float* __restrict__ memory,
    const float* __restrict__ b_in,   const float* __restrict__ b_qkv,
    const float* __restrict__ lnq_g,  const float* __restrict__ lnq_b,
    const float* __restrict__ ln1_g,  const float* __restrict__ ln1_b,
    const float* __restrict__ ln2_g,  const float* __restrict__ ln2_b,
    const float* __restrict__ b_gi,   const float* __restrict__ b_gm,
    const __bf16* __restrict__ wWin,  const __bf16* __restrict__ wWqkv,
    const __bf16* __restrict__ wWc,   const __bf16* __restrict__ wWgi,
    const __bf16* __restrict__ wWgm,  const float* __restrict__ bc,
    float* __restrict__ out0, float* __restrict__ out1)
{
  __shared__ __align__(16) char smem[LDSSZ];
  char* Q = smem;
  char* A = smem + A_OFF;
  char* X = smem + X_OFF;

  const int tid  = threadIdx.x;
  const int lane = tid & 63;
  const int wv   = tid >> 6;
  const int l15  = lane & 15;
  const int lg   = lane >> 4;
  const int b0   = blockIdx.x * BT;
  const float QSC = 0.1020620726159658f;   // 96^-0.5

  // ---- P0: stage inputs (X rows 0..3) & memory (amp rows s*9+j) ----
  if (tid < 64){
    int r = tid >> 4, c = tid & 15;
    const float* gp = inputs + (size_t)(b0+r)*128 + c*8;
    f32x4 a = *(const f32x4*)gp, b = *(const f32x4*)(gp+4);
    bf16x8 h;
    h[0]=(__bf16)a[0]; h[1]=(__bf16)a[1]; h[2]=(__bf16)a[2]; h[3]=(__bf16)a[3];
    h[4]=(__bf16)b[0]; h[5]=(__bf16)b[1]; h[6]=(__bf16)b[2]; h[7]=(__bf16)b[3];
    *(bf16x8*)swz(X, r, 256, c*16) = h;
  }
  for (int t = tid; t < 512; t += 256){            // memory: 32 rows x 16 chunks
    int r = t >> 4, c8 = (t & 15)*8;
    const float* gp = memory + (size_t)(b0 + (r>>3))*1024 + (r&7)*128 + c8;
    f32x4 a = *(const f32x4*)gp, b = *(const f32x4*)(gp+4);
    bf16x8 h;
    h[0]=(__bf16)a[0]; h[1]=(__bf16)a[1]; h[2]=(__bf16)a[2]; h[3]=(__bf16)a[3];
    h[4]=(__bf16)b[0]; h[5]=(__bf16)b[1]; h[6]=(__bf16)b[2]; h[7]=(__bf16)b[3];
    *(bf16x8*)swz(A, (r>>3)*S1 + (r&7), 256, c8*2) = h;
  }
  __syncthreads();

  // ---- P1: x = inputs @ W_in + b_in   (M=4 valid rows, clamped A-tile) ----
  {
    const int xr = (l15 < BT) ? l15 : (BT-1);
    bf16x8 aX[4];
#pragma unroll
    for (int k=0;k<4;k++) aX[k] = *(const bf16x8*)swz(X, xr, 256, k*64 + lg*16);
    f32x4 accX[2];
#pragma unroll
    for (int n=0;n<2;n++){
      int nt = wv*2 + n;
      f32x4 acc = {0.f,0.f,0.f,0.f};
#pragma unroll
      for (int k=0;k<4;k++){
        bf16x8 b = *(const bf16x8*)(wWin + (nt*16 + l15)*128 + k*32 + 8*lg);
        acc = __builtin_amdgcn_mfma_f32_16x16x32_bf16(aX[k], b, acc, 0, 0, 0);
      }
      accX[n] = acc;
    }
    __syncthreads();   // all A-reads of X done before overwrite
#pragma unroll
    for (int n=0;n<2;n++){
#pragma unroll
      for (int r=0;r<4;r++){
        int row = 4*lg + r;
        if (row < BT){
          int col = (wv*2+n)*16 + l15;
          __bf16 h = (__bf16)(accX[n][r] + b_in[col]);
          *(bf16s*)swz(X, row, 256, col*2) = h;            // x (for gi GEMM)
          *(bf16s*)swz(A, row*S1+8, 256, col*2) = h;       // mp slot 8
        }
      }
    }
  }
  __syncthreads();

  // ---- P2: qkv_pre = mp @ W_qkv + b_qkv  (M=36, clamped A-tile rows) ----
  {
    bf16x8 aQ[3][4];
#pragma unroll
    for (int m=0;m<3;m++){
      int ar = m*16 + l15; ar = (ar < RROWS) ? ar : (RROWS-1);
#pragma unroll
      for (int k=0;k<4;k++)
        aQ[m][k] = *(const bf16x8*)swz(A, ar, 256, k*64 + lg*16);
    }
    f32x4 accQ[3][6];
#pragma unroll
    for (int m=0;m<3;m++)
#pragma unroll
      for (int n=0;n<6;n++) accQ[m][n] = (f32x4){0.f,0.f,0.f,0.f};
#pragma unroll
    for (int n=0;n<6;n++){
      int nt = wv*6 + n;
#pragma unroll
      for (int k=0;k<4;k++){
        bf16x8 b = *(const bf16x8*)(wWqkv + (nt*16 + l15)*128 + k*32 + 8*lg);
#pragma unroll
        for (int m=0;m<3;m++)
          accQ[m][n] = __builtin_amdgcn_mfma_f32_16x16x32_bf16(aQ[m][k], b, accQ[m][n], 0, 0, 0);
      }
    }
#pragma unroll
    for (int m=0;m<3;m++)
#pragma unroll
      for (int n=0;n<6;n++)
#pragma unroll
        for (int r=0;r<4;r++){
          int row = m*16 + 4*lg + r;
          if (row < RROWS){
            int col = (wv*6+n)*16 + l15;
            *(bf16s*)swz(Q, row, 768, col*2) = (__bf16)(accQ[m][n][r] + b_qkv[col]);
          }
        }
  }
  __syncthreads();

  // ---- P3: LN(qkv) in place + fold q-scale 96^-0.5 ----
  {
    float gq[6], bq[6];
#pragma unroll
    for (int t=0;t<6;t++){ gq[t] = lnq_g[lane+64*t]; bq[t] = lnq_b[lane+64*t]; }
    for (int r = wv; r < RROWS; r += 4){
      float x[6]; float s = 0.f, sq = 0.f;
#pragma unroll
      for (int t=0;t<6;t++){
        x[t] = (float)*(const bf16s*)swz(Q, r, 768, (lane + 64*t)*2);
        s += x[t]; sq += x[t]*x[t];
      }
#pragma unroll
      for (int o=1;o<64;o<<=1){ s += __shfl_xor(s,o); sq += __shfl_xor(sq,o); }
      float mean = s * (1.f/384.f);
      float var  = sq * (1.f/384.f) - mean*mean;
      float rs   = rsqrtf(var + 1e-5f);
#pragma unroll
      for (int t=0;t<6;t++){
        int c = lane + 64*t;
        float y = gq[t]*(x[t]-mean)*rs + bq[t];
        if ((c % 96) < 32) y *= QSC;
        *(bf16s*)swz(Q, r, 768, c*2) = (__bf16)y;
      }
    }
  }
  __syncthreads();

  // ---- P4: attention (VALU, P in f32 registers). 144 tasks = (s,h,q).
  //      out overwrites the task's OWN dead q-slice (byte-disjoint from K/V). ----
  if (tid < BT*4*S1){
    int s = tid/36, h = (tid/9)&3, q = tid%9;
    int cb = h*192;               // head byte offset within qkv row
    float qv[32];
#pragma unroll
    for (int t=0;t<4;t++){
      bf16x8 hv = *(const bf16x8*)swz(Q, s*S1+q, 768, cb + t*16);
#pragma unroll
      for (int j=0;j<8;j++) qv[t*8+j] = (float)hv[j];
    }
    float sc[9]; float mx = -1e30f;
#pragma unroll
    for (int kk=0;kk<9;kk++){
      float a = 0.f;
#pragma unroll
      for (int t=0;t<4;t++){
        bf16x8 hv = *(const bf16x8*)swz(Q, s*S1+kk, 768, cb + 64 + t*16);
#pragma unroll
        for (int j=0;j<8;j++) a += qv[t*8+j]*(float)hv[j];
      }
      sc[kk] = a; mx = fmaxf(mx, a);
    }
    float sum = 0.f;
#pragma unroll
    for (int kk=0;kk<9;kk++){ sc[kk] = __expf(sc[kk]-mx); sum += sc[kk]; }
    float inv = 1.f/sum;
    float ov[32];
#pragma unroll
    for (int d=0;d<32;d++) ov[d] = 0.f;
#pragma unroll
    for (int kk=0;kk<9;kk++){
      float p = sc[kk];
#pragma unroll
      for (int t=0;t<4;t++){
        bf16x8 hv = *(const bf16x8*)swz(Q, s*S1+kk, 768, cb + 128 + t*16);
#pragma unroll
        for (int j=0;j<8;j++) ov[t*8+j] += p*(float)hv[j];
      }
    }
#pragma unroll
    for (int t=0;t<4;t++){
      bf16x8 hv;
#pragma unroll
      for (int j=0;j<8;j++) hv[j] = (__bf16)(ov[t*8+j]*inv);
      *(bf16x8*)swz(Q, s*S1+q, 768, cb + t*16) = hv;   // out -> own dead q-slice
    }
  }
  __syncthreads();

  // ---- P5: mem = LN(mp + out) -> A in place ----
  {
    float g0 = ln1_g[lane], g1 = ln1_g[lane+64], e0 = ln1_b[lane], e1 = ln1_b[lane+64];
    const int ob0 = (lane>>5)*192 + (lane&31)*2;          // out elem `lane`
    const int ob1 = ((lane>>5)+2)*192 + (lane&31)*2;      // out elem `lane+64`
    for (int r = wv; r < RROWS; r += 4){
      float t0 = (float)*(const bf16s*)swz(A, r, 256, lane*2)
               + (float)*(const bf16s*)swz(Q, r, 768, ob0);
      float t1 = (float)*(const bf16s*)swz(A, r, 256, (lane+64)*2)
               + (float)*(const bf16s*)swz(Q, r, 768, ob1);
      float s = t0+t1, sq = t0*t0 + t1*t1;
#pragma unroll
      for (int o=1;o<64;o<<=1){ s += __shfl_xor(s,o); sq += __shfl_xor(sq,o); }
      float mean = s*(1.f/128.f), var = sq*(1.f/128.f) - mean*mean;
      float rs = rsqrtf(var + 1e-5f);
      *(bf16s*)swz(A, r, 256, lane*2)      = (__bf16)(g0*(t0-mean)*rs + e0);
      *(bf16s*)swz(A, r, 256, (lane+64)*2) = (__bf16)(g1*(t1-mean)*rs + e1);
    }
  }
  __syncthreads();

  // ---- P6: mlp = mem @ (W_m1 W_m2) + bc -> Q f32 [36][512] swz (clamped A rows) ----
  {
    bf16x8 aM[3][4];
#pragma unroll
    for (int m=0;m<3;m++){
      int ar = m*16 + l15; ar = (ar < RROWS) ? ar : (RROWS-1);
#pragma unroll
      for (int k=0;k<4;k++)
        aM[m][k] = *(const bf16x8*)swz(A, ar, 256, k*64 + lg*16);
    }
    f32x4 accM[3][2];
#pragma unroll
    for (int m=0;m<3;m++)
#pragma unroll
      for (int n=0;n<2;n++) accM[m][n] = (f32x4){0.f,0.f,0.f,0.f};
#pragma unroll
    for (int n=0;n<2;n++){
      int nt = wv*2 + n;
#pragma unroll
      for (int k=0;k<4;k++){
        bf16x8 b = *(const bf16x8*)(wWc + (nt*16 + l15)*128 + k*32 + 8*lg);
#pragma unroll
        for (int m=0;m<3;m++)
          accM[m][n] = __builtin_amdgcn_mfma_f32_16x16x32_bf16(aM[m][k], b, accM[m][n], 0, 0, 0);
      }
    }
    __syncthreads();   // Q (qkv+out) fully consumed (P5) before overwrite as mlp
#pragma unroll
    for (int m=0;m<3;m++)
#pragma unroll
      for (int n=0;n<2;n++)
#pragma unroll
        for (int r=0;r<4;r++){
          int row = m*16 + 4*lg + r;
          if (row < RROWS){
            int col = (wv*2+n)*16 + l15;
            *(f32s*)swz(Q, row, 512, col*4) = accM[m][n][r] + bc[col];
          }
        }
  }
  __syncthreads();

  // ---- P7: mem2 = LN(mlp + mem) -> Q+MEM2 bf16 compact [32][256] (skip slot-8) ----
  {
    float g0 = ln2_g[lane], g1 = ln2_g[lane+64], e0 = ln2_b[lane], e1 = ln2_b[lane+64];
    for (int r = wv; r < RROWS; r += 4){
      if ((r % S1) == 8) continue;
      float t0 = *(const f32s*)swz(Q, r, 512, lane*4)
               + (float)*(const bf16s*)swz(A, r, 256, lane*2);
      float t1 = *(const f32s*)swz(Q, r, 512, (lane+64)*4)
               + (float)*(const bf16s*)swz(A, r, 256, (lane+64)*2);
      float s = t0+t1, sq = t0*t0 + t1*t1;
#pragma unroll
      for (int o=1;o<64;o<<=1){ s += __shfl_xor(s,o); sq += __shfl_xor(sq,o); }
      float mean = s*(1.f/128.f), var = sq*(1.f/128.f) - mean*mean;
      float rs = rsqrtf(var + 1e-5f);
      int rp = (r/S1)*8 + (r%S1);                          // compact row s*8+j
      *(bf16s*)swz(Q + MEM2, rp, 256, lane*2)      = (__bf16)(g0*(t0-mean)*rs + e0);
      *(bf16s*)swz(Q + MEM2, rp, 256, (lane+64)*2) = (__bf16)(g1*(t1-mean)*rs + e1);
    }
  }
  __syncthreads();

  // ---- P8: gi = x @ W_gi + b_gi -> gib f32 [4][1024] @Q (over dead mlp);
  //          tanh(memory) -> A compact rows 0..31 ----
  {
    const int xr = (l15 < BT) ? l15 : (BT-1);
    bf16x8 aG[4];
#pragma unroll
    for (int k=0;k<4;k++) aG[k] = *(const bf16x8*)swz(X, xr, 256, k*64 + lg*16);
    f32x4 accG[4];
#pragma unroll
    for (int n=0;n<4;n++) accG[n] = (f32x4){0.f,0.f,0.f,0.f};
#pragma unroll
    for (int n=0;n<4;n++){
      int nt = wv*4 + n;
#pragma unroll
      for (int k=0;k<4;k++){
        bf16x8 b = *(const bf16x8*)(wWgi + (nt*16 + l15)*128 + k*32 + 8*lg);
        accG[n] = __builtin_amdgcn_mfma_f32_16x16x32_bf16(aG[k], b, accG[n], 0, 0, 0);
      }
    }
#pragma unroll
    for (int n=0;n<4;n++)
#pragma unroll
      for (int r=0;r<4;r++){
        int row = 4*lg + r;
        if (row < BT){
          int col = (wv*4+n)*16 + l15;
          *(f32s*)swz(Q, row, 1024, col*4) = accG[n][r] + b_gi[col];
        }
      }
    for (int t = tid; t < 512; t += 256){
      int r = t >> 4, c8 = (t & 15)*8;
      const float* gp = memory + (size_t)(b0 + (r>>3))*1024 + (r&7)*128 + c8;
      f32x4 a = *(const f32x4*)gp, b = *(const f32x4*)(gp+4);
      bf16x8 h;
      h[0]=(__bf16)tanhf_(a[0]); h[1]=(__bf16)tanhf_(a[1]);
      h[2]=(__bf16)tanhf_(a[2]); h[3]=(__bf16)tanhf_(a[3]);
      h[4]=(__bf16)tanhf_(b[0]); h[5]=(__bf16)tanhf_(b[1]);
      h[6]=(__bf16)tanhf_(b[2]); h[7]=(__bf16)tanhf_(b[3]);
      *(bf16x8*)swz(A, r, 256, c8*2) = h;
    }
  }
  __syncthreads();

  // ---- P9: gm = tanh(memory) @ W_gm + b_gm; fused gates -> global ----
  {
    bf16x8 aT[2][4];
#pragma unroll
    for (int m=0;m<2;m++)
#pragma unroll
      for (int k=0;k<4;k++)
        aT[m][k] = *(const bf16x8*)swz(A, m*16 + l15, 256, k*64 + lg*16);
    f32x4 accT[2][4];
#pragma unroll
    for (int m=0;m<2;m++)
#pragma unroll
      for (int t=0;t<4;t++) accT[m][t] = (f32x4){0.f,0.f,0.f,0.f};
    const int ntl[4] = {2*wv, 2*wv+1, 8+2*wv, 8+2*wv+1};
#pragma unroll
    for (int t=0;t<4;t++){
#pragma unroll
      for (int k=0;k<4;k++){
        bf16x8 b = *(const bf16x8*)(wWgm + (ntl[t]*16 + l15)*128 + k*32 + 8*lg);
#pragma unroll
        for (int m=0;m<2;m++)
          accT[m][t] = __builtin_amdgcn_mfma_f32_16x16x32_bf16(aT[m][k], b, accT[m][t], 0, 0, 0);
      }
    }
#pragma unroll
    for (int m=0;m<2;m++)
#pragma unroll
      for (int p=0;p<2;p++)
#pragma unroll
        for (int r=0;r<4;r++){
          int row = m*16 + 4*lg + r;       // 0..31 = s*8+j
          int s = row>>3, j = row&7;
          int c = wv*32 + p*16 + l15;      // 0..127
          float g_i = accT[m][p][r]   + b_gm[c]
                    + *(const f32s*)swz(Q, s, 1024, c*4);
          float g_f = accT[m][2+p][r] + b_gm[128+c]
                    + *(const f32s*)swz(Q, s, 1024, (128+c)*4) + 1.0f;
          float ig = sigmoidf_(g_i), fg = sigmoidf_(g_f);
          float m2 = (float)*(const bf16s*)swz(Q + MEM2, row, 256, c*2);
          float mo = memory[(size_t)(b0+s)*1024 + j*128 + c];
          float nm = ig*tanhf_(m2) + fg*mo;
          size_t o = (size_t)(b0+s)*1024 + (size_t)(j*128 + c);
          out0[o] = nm;
          out1[o] = nm;
        }
  }
}

// ---------------- launch ----------------
extern "C" void kernel_launch(void* const* d_in, const int* in_sizes, int n_in,
                              void* d_out, int out_size, void* d_ws, size_t ws_size,
                              hipStream_t stream) {
  const float* inputs = (const float*)d_in[0];
  const float* memory = (const float*)d_in[1];
  const float* W_in   = (const float*)d_in[2];
  const float* b_in   = (const float*)d_in[3];
  const float* W_qkv  = (const float*)d_in[4];
  const float* b_qkv  = (const float*)d_in[5];
  const float* lnq_g  = (const float*)d_in[6];
  const float* lnq_b  = (const float*)d_in[7];
  const float* ln1_g  = (const float*)d_in[8];
  const float* ln1_b  = (const float*)d_in[9];
  const float* W_m1   = (const float*)d_in[10];
  const float* b_m1   = (const float*)d_in[11];
  const float* W_m2   = (const float*)d_in[12];
  const float* b_m2   = (const float*)d_in[13];
  const float* ln2_g  = (const float*)d_in[14];
  const float* ln2_b  = (const float*)d_in[15];
  const float* W_gi   = (const float*)d_in[16];
  const float* b_gi   = (const float*)d_in[17];
  const float* W_gm   = (const float*)d_in[18];
  const float* b_gm   = (const float*)d_in[19];

  __bf16* ws16 = (__bf16*)d_ws;
  float* bcp = (float*)((char*)d_ws + WS_BC);
  const __bf16* wWin  = (const __bf16*)((char*)d_ws + WS_WIN);
  const __bf16* wWqkv = (const __bf16*)((char*)d_ws + WS_WQKV);
  const __bf16* wWc   = (const __bf16*)((char*)d_ws + WS_WC);
  const __bf16* wWgi  = (const __bf16*)((char*)d_ws + WS_WGI);
  const __bf16* wWgm  = (const __bf16*)((char*)d_ws + WS_WGM);

  float* out0 = (float*)d_out;
  float* out1 = out0 + (size_t)BATCH*1024;

  prep_kernel<<<dim3(256), dim3(256), 0, stream>>>(
      W_in, W_qkv, W_m1, W_m2, b_m1, b_m2, W_gi, W_gm, ws16, bcp);

  rmc_kernel<<<dim3(NBLK), dim3(256), 0, stream>>>(
      inputs, memory, b_in, b_qkv, lnq_g, lnq_b, ln1_g, ln1_b, ln2_g, ln2_b,
      b_gi, b_gm, wWin, wWqkv, wWc, wWgi, wWgm, bcp, out0, out1);
}

// Round 10
// 668.677 us; speedup vs baseline: 2.1795x; 1.5310x over previous
//
#include <hip/hip_runtime.h>
#include <cstdint>
#include <cstddef>

// ---------------- constants ----------------
#define BATCH   32768
#define BT      4            // samples per workgroup
#define S1      9            // SLOTS+1
#define RROWS   36           // BT*S1
#define NBLK    (BATCH/BT)   // 8192

// d_ws byte offsets (bf16 transposed weights + collapsed MLP)
#define WS_WIN   0            // [128][128] bf16  WinT[n][k] = W_in[k][n]
#define WS_WQKV  32768        // [384][128] bf16
#define WS_WC    131072       // [128][128] bf16  (W_m1 @ W_m2)^T
#define WS_WGI   163840       // [256][128] bf16
#define WS_WGM   229376       // [256][128] bf16
#define WS_BC    294912       // [128] f32        b_m1 @ W_m2 + b_m2

// LDS plan (37888 B; with VGPR<=128 -> 4 blocks/CU, the target of this round):
//  Q [0,27648)      qkv bf16 [36][768B] swz. attn-out overwrites dead q-slices (P4).
//                   Later: mlp f32 [36][512B] swz @0 (P6); mem2 bf16 [32][256B] swz @19456
//                   compact rows s*8+j (P7); gib f32 [4][1024B] swz @0 (P8, over dead mlp).
//  A [27648,36864)  amp bf16 [36][256B] swz: mp rows s*9+slot -> mem (P5 in place) ->
//                   tanh(memory) compact [32] rows (P8).
//  X [36864,37888)  x bf16 [4][256B] swz: staged inputs -> x (P1 in place).
// No zero padding: A-fragment row indices are CLAMPED (duplicate rows only affect
// C rows that are discarded by row guards).
#define A_OFF  27648
#define X_OFF  36864
#define MEM2   19456
#define LDSSZ  37888

typedef __bf16 bf16x8 __attribute__((ext_vector_type(8), may_alias));
typedef __bf16 bf16x4 __attribute__((ext_vector_type(4), may_alias));
typedef float  f32x4  __attribute__((ext_vector_type(4), may_alias));
typedef __bf16 bf16s  __attribute__((may_alias));
typedef float  f32s   __attribute__((may_alias));

__device__ __forceinline__ float sigmoidf_(float x){ return 1.f/(1.f+__expf(-x)); }
__device__ __forceinline__ float tanhf_(float x){ float e = __expf(2.f*x); return 1.f - 2.f/(e+1.f); }

// XOR bank swizzle: permute 16B blocks within each row by row&7 (T2 recipe).
__device__ __forceinline__ char* swz(char* base, int row, int stride, int colb){
  return base + row*stride + (colb ^ ((row & 7) << 4));
}

// ---------------- weight prep: f32 -> bf16 transposed, W_m1@W_m2 collapsed ----------------
__global__ __launch_bounds__(256) void prep_kernel(
    const float* __restrict__ W_in,  const float* __restrict__ W_qkv,
    const float* __restrict__ W_m1,  const float* __restrict__ W_m2,
    const float* __restrict__ b_m1,  const float* __restrict__ b_m2,
    const float* __restrict__ W_gi,  const float* __restrict__ W_gm,
    __bf16* __restrict__ ws, float* __restrict__ bc)
{
  int gt = blockIdx.x*256 + threadIdx.x;
  int NT = gridDim.x*256;
  for (int i = gt; i < 128*128; i += NT){ int n=i>>7, k=i&127; ws[(WS_WIN >>1)+i] = (__bf16)W_in [k*128+n]; }
  for (int i = gt; i < 384*128; i += NT){ int n=i>>7, k=i&127; ws[(WS_WQKV>>1)+i] = (__bf16)W_qkv[k*384+n]; }
  for (int i = gt; i < 256*128; i += NT){ int n=i>>7, k=i&127; ws[(WS_WGI >>1)+i] = (__bf16)W_gi [k*256+n]; }
  for (int i = gt; i < 256*128; i += NT){ int n=i>>7, k=i&127; ws[(WS_WGM >>1)+i] = (__bf16)W_gm [k*256+n]; }
  for (int i = gt; i < 128*128; i += NT){
    int n=i>>7, k=i&127;
    float s = 0.f;
    for (int j=0;j<128;j++) s += W_m1[k*128+j]*W_m2[j*128+n];
    ws[(WS_WC>>1)+i] = (__bf16)s;
  }
  for (int i = gt; i < 128; i += NT){
    float s = b_m2[i];
    for (int j=0;j<128;j++) s += b_m1[j]*W_m2[j*128+i];
    bc[i] = s;
  }
}

// ---------------- fused main kernel (block-cooperative) ----------------
// __launch_bounds__(256,4): min 4 waves/EU -> VGPR cap 128 -> 4 blocks/CU (LDS allows 4).
// This is safe ONLY because P2 was restructured (n-loop split in two halves) so peak
// pressure ~110 fits under 128 without spills. Tripwire: WRITE_SIZE must stay 262144 KB.
__global__ __launch_bounds__(256, 4) void rmc_kernel(
    const float* __restrict__ inputs, const float* __restrict__ memory,
    const float* __restrict__ b_in,   const float* __restrict__ b_qkv,
    const float* __restrict__ lnq_g,  const float* __restrict__ lnq_b,
    const float* __restrict__ ln1_g,  const float* __restrict__ ln1_b,
    const float* __restrict__ ln2_g,  const float* __restrict__ ln2_b,
    const float* __restrict__ b_gi,   const float* __restrict__ b_gm,
    const __bf16* __restrict__ wWin,  const __bf16* __restrict__ wWqkv,
    const __bf16* __restrict__ wWc,   const __bf16* __restrict__ wWgi,
    const __bf16* __restrict__ wWgm,  const float* __restrict__ bc,
    float* __restrict__ out0, float* __restrict__ out1)
{
  __shared__ __align__(16) char smem[LDSSZ];
  char* Q = smem;
  char* A = smem + A_OFF;
  char* X = smem + X_OFF;

  const int tid  = threadIdx.x;
  const int lane = tid & 63;
  const int wv   = tid >> 6;
  const int l15  = lane & 15;
  const int lg   = lane >> 4;
  const int b0   = blockIdx.x * BT;
  const float QSC = 0.1020620726159658f;   // 96^-0.5

  // ---- P0: stage inputs (X rows 0..3) & memory (amp rows s*9+j) ----
  if (tid < 64){
    int r = tid >> 4, c = tid & 15;
    const float* gp = inputs + (size_t)(b0+r)*128 + c*8;
    f32x4 a = *(const f32x4*)gp, b = *(const f32x4*)(gp+4);
    bf16x8 h;
    h[0]=(__bf16)a[0]; h[1]=(__bf16)a[1]; h[2]=(__bf16)a[2]; h[3]=(__bf16)a[3];
    h[4]=(__bf16)b[0]; h[5]=(__bf16)b[1]; h[6]=(__bf16)b[2]; h[7]=(__bf16)b[3];
    *(bf16x8*)swz(X, r, 256, c*16) = h;
  }
  for (int t = tid; t < 512; t += 256){            // memory: 32 rows x 16 chunks
    int r = t >> 4, c8 = (t & 15)*8;
    const float* gp = memory + (size_t)(b0 + (r>>3))*1024 + (r&7)*128 + c8;
    f32x4 a = *(const f32x4*)gp, b = *(const f32x4*)(gp+4);
    bf16x8 h;
    h[0]=(__bf16)a[0]; h[1]=(__bf16)a[1]; h[2]=(__bf16)a[2]; h[3]=(__bf16)a[3];
    h[4]=(__bf16)b[0]; h[5]=(__bf16)b[1]; h[6]=(__bf16)b[2]; h[7]=(__bf16)b[3];
    *(bf16x8*)swz(A, (r>>3)*S1 + (r&7), 256, c8*2) = h;
  }
  __syncthreads();

  // ---- P1: x = inputs @ W_in + b_in   (M=4 valid rows, clamped A-tile) ----
  {
    const int xr = (l15 < BT) ? l15 : (BT-1);
    bf16x8 aX[4];
#pragma unroll
    for (int k=0;k<4;k++) aX[k] = *(const bf16x8*)swz(X, xr, 256, k*64 + lg*16);
    f32x4 accX[2];
#pragma unroll
    for (int n=0;n<2;n++){
      int nt = wv*2 + n;
      f32x4 acc = {0.f,0.f,0.f,0.f};
#pragma unroll
      for (int k=0;k<4;k++){
        bf16x8 b = *(const bf16x8*)(wWin + (nt*16 + l15)*128 + k*32 + 8*lg);
        acc = __builtin_amdgcn_mfma_f32_16x16x32_bf16(aX[k], b, acc, 0, 0, 0);
      }
      accX[n] = acc;
    }
    __syncthreads();   // all A-reads of X done before overwrite
#pragma unroll
    for (int n=0;n<2;n++){
#pragma unroll
      for (int r=0;r<4;r++){
        int row = 4*lg + r;
        if (row < BT){
          int col = (wv*2+n)*16 + l15;
          __bf16 h = (__bf16)(accX[n][r] + b_in[col]);
          *(bf16s*)swz(X, row, 256, col*2) = h;            // x (for gi GEMM)
          *(bf16s*)swz(A, row*S1+8, 256, col*2) = h;       // mp slot 8
        }
      }
    }
  }
  __syncthreads();

  // ---- P2: qkv_pre = mp @ W_qkv + b_qkv  (M=36, clamped A rows).
  //      n-loop split in 2 halves of 3 tiles: accQ[3][3]=36 regs instead of 72 ->
  //      peak pressure fits the 128-VGPR cap (4 blocks/CU) without spills. ----
  {
    bf16x8 aQ[3][4];
#pragma unroll
    for (int m=0;m<3;m++){
      int ar = m*16 + l15; ar = (ar < RROWS) ? ar : (RROWS-1);
#pragma unroll
      for (int k=0;k<4;k++)
        aQ[m][k] = *(const bf16x8*)swz(A, ar, 256, k*64 + lg*16);
    }
#pragma unroll
    for (int half=0; half<2; ++half){
      f32x4 accQ[3][3];
#pragma unroll
      for (int m=0;m<3;m++)
#pragma unroll
        for (int n=0;n<3;n++) accQ[m][n] = (f32x4){0.f,0.f,0.f,0.f};
#pragma unroll
      for (int n=0;n<3;n++){
        int nt = wv*6 + half*3 + n;
#pragma unroll
        for (int k=0;k<4;k++){
          bf16x8 b = *(const bf16x8*)(wWqkv + (nt*16 + l15)*128 + k*32 + 8*lg);
#pragma unroll
          for (int m=0;m<3;m++)
            accQ[m][n] = __builtin_amdgcn_mfma_f32_16x16x32_bf16(aQ[m][k], b, accQ[m][n], 0, 0, 0);
        }
      }
#pragma unroll
      for (int m=0;m<3;m++)
#pragma unroll
        for (int n=0;n<3;n++)
#pragma unroll
          for (int r=0;r<4;r++){
            int row = m*16 + 4*lg + r;
            if (row < RROWS){
              int col = (wv*6 + half*3 + n)*16 + l15;
              *(bf16s*)swz(Q, row, 768, col*2) = (__bf16)(accQ[m][n][r] + b_qkv[col]);
            }
          }
    }
  }
  __syncthreads();

  // ---- P3: LN(qkv) in place + fold q-scale 96^-0.5 ----
  {
    float gq[6], bq[6];
#pragma unroll
    for (int t=0;t<6;t++){ gq[t] = lnq_g[lane+64*t]; bq[t] = lnq_b[lane+64*t]; }
    for (int r = wv; r < RROWS; r += 4){
      float x[6]; float s = 0.f, sq = 0.f;
#pragma unroll
      for (int t=0;t<6;t++){
        x[t] = (float)*(const bf16s*)swz(Q, r, 768, (lane + 64*t)*2);
        s += x[t]; sq += x[t]*x[t];
      }
#pragma unroll
      for (int o=1;o<64;o<<=1){ s += __shfl_xor(s,o); sq += __shfl_xor(sq,o); }
      float mean = s * (1.f/384.f);
      float var  = sq * (1.f/384.f) - mean*mean;
      float rs   = rsqrtf(var + 1e-5f);
#pragma unroll
      for (int t=0;t<6;t++){
        int c = lane + 64*t;
        float y = gq[t]*(x[t]-mean)*rs + bq[t];
        if ((c % 96) < 32) y *= QSC;
        *(bf16s*)swz(Q, r, 768, c*2) = (__bf16)y;
      }
    }
  }
  __syncthreads();

  // ---- P4: attention (VALU, P in f32 registers). 144 tasks = (s,h,q).
  //      out overwrites the task's OWN dead q-slice (byte-disjoint from K/V). ----
  if (tid < BT*4*S1){
    int s = tid/36, h = (tid/9)&3, q = tid%9;
    int cb = h*192;               // head byte offset within qkv row
    float qv[32];
#pragma unroll
    for (int t=0;t<4;t++){
      bf16x8 hv = *(const bf16x8*)swz(Q, s*S1+q, 768, cb + t*16);
#pragma unroll
      for (int j=0;j<8;j++) qv[t*8+j] = (float)hv[j];
    }
    float sc[9]; float mx = -1e30f;
#pragma unroll
    for (int kk=0;kk<9;kk++){
      float a = 0.f;
#pragma unroll
      for (int t=0;t<4;t++){
        bf16x8 hv = *(const bf16x8*)swz(Q, s*S1+kk, 768, cb + 64 + t*16);
#pragma unroll
        for (int j=0;j<8;j++) a += qv[t*8+j]*(float)hv[j];
      }
      sc[kk] = a; mx = fmaxf(mx, a);
    }
    float sum = 0.f;
#pragma unroll
    for (int kk=0;kk<9;kk++){ sc[kk] = __expf(sc[kk]-mx); sum += sc[kk]; }
    float inv = 1.f/sum;
    float ov[32];
#pragma unroll
    for (int d=0;d<32;d++) ov[d] = 0.f;
#pragma unroll
    for (int kk=0;kk<9;kk++){
      float p = sc[kk];
#pragma unroll
      for (int t=0;t<4;t++){
        bf16x8 hv = *(const bf16x8*)swz(Q, s*S1+kk, 768, cb + 128 + t*16);
#pragma unroll
        for (int j=0;j<8;j++) ov[t*8+j] += p*(float)hv[j];
      }
    }
#pragma unroll
    for (int t=0;t<4;t++){
      bf16x8 hv;
#pragma unroll
      for (int j=0;j<8;j++) hv[j] = (__bf16)(ov[t*8+j]*inv);
      *(bf16x8*)swz(Q, s*S1+q, 768, cb + t*16) = hv;   // out -> own dead q-slice
    }
  }
  __syncthreads();

  // ---- P5: mem = LN(mp + out) -> A in place ----
  {
    float g0 = ln1_g[lane], g1 = ln1_g[lane+64], e0 = ln1_b[lane], e1 = ln1_b[lane+64];
    const int ob0 = (lane>>5)*192 + (lane&31)*2;          // out elem `lane`
    const int ob1 = ((lane>>5)+2)*192 + (lane&31)*2;      // out elem `lane+64`
    for (int r = wv; r < RROWS; r += 4){
      float t0 = (float)*(const bf16s*)swz(A, r, 256, lane*2)
               + (float)*(const bf16s*)swz(Q, r, 768, ob0);
      float t1 = (float)*(const bf16s*)swz(A, r, 256, (lane+64)*2)
               + (float)*(const bf16s*)swz(Q, r, 768, ob1);
      float s = t0+t1, sq = t0*t0 + t1*t1;
#pragma unroll
      for (int o=1;o<64;o<<=1){ s += __shfl_xor(s,o); sq += __shfl_xor(sq,o); }
      float mean = s*(1.f/128.f), var = sq*(1.f/128.f) - mean*mean;
      float rs = rsqrtf(var + 1e-5f);
      *(bf16s*)swz(A, r, 256, lane*2)      = (__bf16)(g0*(t0-mean)*rs + e0);
      *(bf16s*)swz(A, r, 256, (lane+64)*2) = (__bf16)(g1*(t1-mean)*rs + e1);
    }
  }
  __syncthreads();

  // ---- P6: mlp = mem @ (W_m1 W_m2) + bc -> Q f32 [36][512] swz (clamped A rows) ----
  {
    bf16x8 aM[3][4];
#pragma unroll
    for (int m=0;m<3;m++){
      int ar = m*16 + l15; ar = (ar < RROWS) ? ar : (RROWS-1);
#pragma unroll
      for (int k=0;k<4;k++)
        aM[m][k] = *(const bf16x8*)swz(A, ar, 256, k*64 + lg*16);
    }
    f32x4 accM[3][2];
#pragma unroll
    for (int m=0;m<3;m++)
#pragma unroll
      for (int n=0;n<2;n++) accM[m][n] = (f32x4){0.f,0.f,0.f,0.f};
#pragma unroll
    for (int n=0;n<2;n++){
      int nt = wv*2 + n;
#pragma unroll
      for (int k=0;k<4;k++){
        bf16x8 b = *(const bf16x8*)(wWc + (nt*16 + l15)*128 + k*32 + 8*lg);
#pragma unroll
        for (int m=0;m<3;m++)
          accM[m][n] = __builtin_amdgcn_mfma_f32_16x16x32_bf16(aM[m][k], b, accM[m][n], 0, 0, 0);
      }
    }
    __syncthreads();   // Q (qkv+out) fully consumed (P5) before overwrite as mlp
#pragma unroll
    for (int m=0;m<3;m++)
#pragma unroll
      for (int n=0;n<2;n++)
#pragma unroll
        for (int r=0;r<4;r++){
          int row = m*16 + 4*lg + r;
          if (row < RROWS){
            int col = (wv*2+n)*16 + l15;
            *(f32s*)swz(Q, row, 512, col*4) = accM[m][n][r] + bc[col];
          }
        }
  }
  __syncthreads();

  // ---- P7: mem2 = LN(mlp + mem) -> Q+MEM2 bf16 compact [32][256] (skip slot-8) ----
  {
    float g0 = ln2_g[lane], g1 = ln2_g[lane+64], e0 = ln2_b[lane], e1 = ln2_b[lane+64];
    for (int r = wv; r < RROWS; r += 4){
      if ((r % S1) == 8) continue;
      float t0 = *(const f32s*)swz(Q, r, 512, lane*4)
               + (float)*(const bf16s*)swz(A, r, 256, lane*2);
      float t1 = *(const f32s*)swz(Q, r, 512, (lane+64)*4)
               + (float)*(const bf16s*)swz(A, r, 256, (lane+64)*2);
      float s = t0+t1, sq = t0*t0 + t1*t1;
#pragma unroll
      for (int o=1;o<64;o<<=1){ s += __shfl_xor(s,o); sq += __shfl_xor(sq,o); }
      float mean = s*(1.f/128.f), var = sq*(1.f/128.f) - mean*mean;
      float rs = rsqrtf(var + 1e-5f);
      int rp = (r/S1)*8 + (r%S1);                          // compact row s*8+j
      *(bf16s*)swz(Q + MEM2, rp, 256, lane*2)      = (__bf16)(g0*(t0-mean)*rs + e0);
      *(bf16s*)swz(Q + MEM2, rp, 256, (lane+64)*2) = (__bf16)(g1*(t1-mean)*rs + e1);
    }
  }
  __syncthreads();

  // ---- P8: gi = x @ W_gi + b_gi -> gib f32 [4][1024] @Q (over dead mlp);
  //          tanh(memory) -> A compact rows 0..31 ----
  {
    const int xr = (l15 < BT) ? l15 : (BT-1);
    bf16x8 aG[4];
#pragma unroll
    for (int k=0;k<4;k++) aG[k] = *(const bf16x8*)swz(X, xr, 256, k*64 + lg*16);
    f32x4 accG[4];
#pragma unroll
    for (int n=0;n<4;n++) accG[n] = (f32x4){0.f,0.f,0.f,0.f};
#pragma unroll
    for (int n=0;n<4;n++){
      int nt = wv*4 + n;
#pragma unroll
      for (int k=0;k<4;k++){
        bf16x8 b = *(const bf16x8*)(wWgi + (nt*16 + l15)*128 + k*32 + 8*lg);
        accG[n] = __builtin_amdgcn_mfma_f32_16x16x32_bf16(aG[k], b, accG[n], 0, 0, 0);
      }
    }
#pragma unroll
    for (int n=0;n<4;n++)
#pragma unroll
      for (int r=0;r<4;r++){
        int row = 4*lg + r;
        if (row < BT){
          int col = (wv*4+n)*16 + l15;
          *(f32s*)swz(Q, row, 1024, col*4) = accG[n][r] + b_gi[col];
        }
      }
    for (int t = tid; t < 512; t += 256){
      int r = t >> 4, c8 = (t & 15)*8;
      const float* gp = memory + (size_t)(b0 + (r>>3))*1024 + (r&7)*128 + c8;
      f32x4 a = *(const f32x4*)gp, b = *(const f32x4*)(gp+4);
      bf16x8 h;
      h[0]=(__bf16)tanhf_(a[0]); h[1]=(__bf16)tanhf_(a[1]);
      h[2]=(__bf16)tanhf_(a[2]); h[3]=(__bf16)tanhf_(a[3]);
      h[4]=(__bf16)tanhf_(b[0]); h[5]=(__bf16)tanhf_(b[1]);
      h[6]=(__bf16)tanhf_(b[2]); h[7]=(__bf16)tanhf_(b[3]);
      *(bf16x8*)swz(A, r, 256, c8*2) = h;
    }
  }
  __syncthreads();

  // ---- P9: gm = tanh(memory) @ W_gm + b_gm; fused gates -> global ----
  {
    bf16x8 aT[2][4];
#pragma unroll
    for (int m=0;m<2;m++)
#pragma unroll
      for (int k=0;k<4;k++)
        aT[m][k] = *(const bf16x8*)swz(A, m*16 + l15, 256, k*64 + lg*16);
    f32x4 accT[2][4];
#pragma unroll
    for (int m=0;m<2;m++)
#pragma unroll
      for (int t=0;t<4;t++) accT[m][t] = (f32x4){0.f,0.f,0.f,0.f};
    const int ntl[4] = {2*wv, 2*wv+1, 8+2*wv, 8+2*wv+1};
#pragma unroll
    for (int t=0;t<4;t++){
#pragma unroll
      for (int k=0;k<4;k++){
        bf16x8 b = *(const bf16x8*)(wWgm + (ntl[t]*16 + l15)*128 + k*32 + 8*lg);
#pragma unroll
        for (int m=0;m<2;m++)
          accT[m][t] = __builtin_amdgcn_mfma_f32_16x16x32_bf16(aT[m][k], b, accT[m][t], 0, 0, 0);
      }
    }
#pragma unroll
    for (int m=0;m<2;m++)
#pragma unroll
      for (int p=0;p<2;p++)
#pragma unroll
        for (int r=0;r<4;r++){
          int row = m*16 + 4*lg + r;       // 0..31 = s*8+j
          int s = row>>3, j = row&7;
          int c = wv*32 + p*16 + l15;      // 0..127
          float g_i = accT[m][p][r]   + b_gm[c]
                    + *(const f32s*)swz(Q, s, 1024, c*4);
          float g_f = accT[m][2+p][r] + b_gm[128+c]
                    + *(const f32s*)swz(Q, s, 1024, (128+c)*4) + 1.0f;
          float ig = sigmoidf_(g_i), fg = sigmoidf_(g_f);
          float m2 = (float)*(const bf16s*)swz(Q + MEM2, row, 256, c*2);
          float mo = memory[(size_t)(b0+s)*1024 + j*128 + c];
          float nm = ig*tanhf_(m2) + fg*mo;
          size_t o = (size_t)(b0+s)*1024 + (size_t)(j*128 + c);
          out0[o] = nm;
          out1[o] = nm;
        }
  }
}

// ---------------- launch ----------------
extern "C" void kernel_launch(void* const* d_in, const int* in_sizes, int n_in,
                              void* d_out, int out_size, void* d_ws, size_t ws_size,
                              hipStream_t stream) {
  const float* inputs = (const float*)d_in[0];
  const float* memory = (const float*)d_in[1];
  const float* W_in   = (const float*)d_in[2];
  const float* b_in   = (const float*)d_in[3];
  const float* W_qkv  = (const float*)d_in[4];
  const float* b_qkv  = (const float*)d_in[5];
  const float* lnq_g  = (const float*)d_in[6];
  const float* lnq_b  = (const float*)d_in[7];
  const float* ln1_g  = (const float*)d_in[8];
  const float* ln1_b  = (const float*)d_in[9];
  const float* W_m1   = (const float*)d_in[10];
  const float* b_m1   = (const float*)d_in[11];
  const float* W_m2   = (const float*)d_in[12];
  const float* b_m2   = (const float*)d_in[13];
  const float* ln2_g  = (const float*)d_in[14];
  const float* ln2_b  = (const float*)d_in[15];
  const float* W_gi   = (const float*)d_in[16];
  const float* b_gi   = (const float*)d_in[17];
  const float* W_gm   = (const float*)d_in[18];
  const float* b_gm   = (const float*)d_in[19];

  __bf16* ws16 = (__bf16*)d_ws;
  float* bcp = (float*)((char*)d_ws + WS_BC);
  const __bf16* wWin  = (const __bf16*)((char*)d_ws + WS_WIN);
  const __bf16* wWqkv = (const __bf16*)((char*)d_ws + WS_WQKV);
  const __bf16* wWc   = (const __bf16*)((char*)d_ws + WS_WC);
  const __bf16* wWgi  = (const __bf16*)((char*)d_ws + WS_WGI);
  const __bf16* wWgm  = (const __bf16*)((char*)d_ws + WS_WGM);

  float* out0 = (float*)d_out;
  float* out1 = out0 + (size_t)BATCH*1024;

  prep_kernel<<<dim3(256), dim3(256), 0, stream>>>(
      W_in, W_qkv, W_m1, W_m2, b_m1, b_m2, W_gi, W_gm, ws16, bcp);

  rmc_kernel<<<dim3(NBLK), dim3(256), 0, stream>>>(
      inputs, memory, b_in, b_qkv, lnq_g, lnq_b, ln1_g, ln1_b, ln2_g, ln2_b,
      b_gi, b_gm, wWin, wWqkv, wWc, wWgi, wWgm, bcp, out0, out1);
}

// Round 11
// 563.193 us; speedup vs baseline: 2.5877x; 1.1873x over previous
//
#include <hip/hip_runtime.h>
#include <cstdint>
#include <cstddef>

// ---------------- constants ----------------
#define BATCH   32768
#define BT      4            // samples per workgroup
#define S1      9            // SLOTS+1
#define RROWS   36           // BT*S1
#define NBLK    (BATCH/BT)   // 8192

// d_ws byte offsets (bf16 transposed weights + collapsed MLP)
#define WS_WIN   0            // [128][128] bf16  WinT[n][k] = W_in[k][n]
#define WS_WQKV  32768        // [384][128] bf16
#define WS_WC    131072       // [128][128] bf16  (W_m1 @ W_m2)^T
#define WS_WGI   163840       // [256][128] bf16
#define WS_WGM   229376       // [256][128] bf16
#define WS_BC    294912       // [128] f32        b_m1 @ W_m2 + b_m2

// LDS plan (37888 B; 4 blocks/CU under launch_bounds(256,4)):
//  Q [0,27648)      qkv bf16 [36][768B] swz. P4: P f32 (36B) then attn-out (64B) live in
//                   dead q-slices. Later: mlp f32 [36][512B] @0 (P6); mem2 bf16 [32][256B]
//                   @19456 compact (P7); gib f32 [4][1024B] @0 (P8, over dead mlp).
//  A [27648,36864)  amp bf16 [36][256B] swz: mp -> mem (P5 in place) -> tanh(memory) (P8).
//  X [36864,37888)  x bf16 [4][256B] swz: staged inputs -> x (P1 in place).
// No zero padding: A-fragment rows CLAMPED (dups only feed discarded C rows).
#define A_OFF  27648
#define X_OFF  36864
#define MEM2   19456
#define LDSSZ  37888

typedef __bf16 bf16x8 __attribute__((ext_vector_type(8), may_alias));
typedef __bf16 bf16x4 __attribute__((ext_vector_type(4), may_alias));
typedef float  f32x4  __attribute__((ext_vector_type(4), may_alias));
typedef __bf16 bf16s  __attribute__((may_alias));
typedef float  f32s   __attribute__((may_alias));

__device__ __forceinline__ float sigmoidf_(float x){ return 1.f/(1.f+__expf(-x)); }
__device__ __forceinline__ float tanhf_(float x){ float e = __expf(2.f*x); return 1.f - 2.f/(e+1.f); }

// XOR bank swizzle: permute 16B blocks within each row by row&7 (T2 recipe).
__device__ __forceinline__ char* swz(char* base, int row, int stride, int colb){
  return base + row*stride + (colb ^ ((row & 7) << 4));
}

// ---------------- weight prep: f32 -> bf16 transposed, W_m1@W_m2 collapsed ----------------
__global__ __launch_bounds__(256) void prep_kernel(
    const float* __restrict__ W_in,  const float* __restrict__ W_qkv,
    const float* __restrict__ W_m1,  const float* __restrict__ W_m2,
    const float* __restrict__ b_m1,  const float* __restrict__ b_m2,
    const float* __restrict__ W_gi,  const float* __restrict__ W_gm,
    __bf16* __restrict__ ws, float* __restrict__ bc)
{
  int gt = blockIdx.x*256 + threadIdx.x;
  int NT = gridDim.x*256;
  for (int i = gt; i < 128*128; i += NT){ int n=i>>7, k=i&127; ws[(WS_WIN >>1)+i] = (__bf16)W_in [k*128+n]; }
  for (int i = gt; i < 384*128; i += NT){ int n=i>>7, k=i&127; ws[(WS_WQKV>>1)+i] = (__bf16)W_qkv[k*384+n]; }
  for (int i = gt; i < 256*128; i += NT){ int n=i>>7, k=i&127; ws[(WS_WGI >>1)+i] = (__bf16)W_gi [k*256+n]; }
  for (int i = gt; i < 256*128; i += NT){ int n=i>>7, k=i&127; ws[(WS_WGM >>1)+i] = (__bf16)W_gm [k*256+n]; }
  for (int i = gt; i < 128*128; i += NT){
    int n=i>>7, k=i&127;
    float s = 0.f;
    for (int j=0;j<128;j++) s += W_m1[k*128+j]*W_m2[j*128+n];
    ws[(WS_WC>>1)+i] = (__bf16)s;
  }
  for (int i = gt; i < 128; i += NT){
    float s = b_m2[i];
    for (int j=0;j<128;j++) s += b_m1[j]*W_m2[j*128+i];
    bc[i] = s;
  }
}

// ---------------- fused main kernel (block-cooperative) ----------------
// launch_bounds(256,4): 4 blocks/CU. P4/P9 restructured so peak *arch-VGPR* demand
// fits the ~64-reg split allocation (R10's spills came from P4's 75 live VALU floats).
// Spill tripwire: WRITE_SIZE must be ~262144 KB (pure output).
__global__ __launch_bounds__(256, 4) void rmc_kernel(
    const float* __restrict__ inputs, const float* __restrict__ memory,
    const float* __restrict__ b_in,   const float* __restrict__ b_qkv,
    const float* __restrict__ lnq_g,  const float* __restrict__ lnq_b,
    const float* __restrict__ ln1_g,  const float* __restrict__ ln1_b,
    const float* __restrict__ ln2_g,  const float* __restrict__ ln2_b,
    const float* __restrict__ b_gi,   const float* __restrict__ b_gm,
    const __bf16* __restrict__ wWin,  const __bf16* __restrict__ wWqkv,
    const __bf16* __restrict__ wWc,   const __bf16* __restrict__ wWgi,
    const __bf16* __restrict__ wWgm,  const float* __restrict__ bc,
    float* __restrict__ out0, float* __restrict__ out1)
{
  __shared__ __align__(16) char smem[LDSSZ];
  char* Q = smem;
  char* A = smem + A_OFF;
  char* X = smem + X_OFF;

  const int tid  = threadIdx.x;
  const int lane = tid & 63;
  const int wv   = tid >> 6;
  const int l15  = lane & 15;
  const int lg   = lane >> 4;
  const int b0   = blockIdx.x * BT;
  const float QSC = 0.1020620726159658f;   // 96^-0.5

  // ---- P0: stage inputs (X rows 0..3) & memory (amp rows s*9+j) ----
  if (tid < 64){
    int r = tid >> 4, c = tid & 15;
    const float* gp = inputs + (size_t)(b0+r)*128 + c*8;
    f32x4 a = *(const f32x4*)gp, b = *(const f32x4*)(gp+4);
    bf16x8 h;
    h[0]=(__bf16)a[0]; h[1]=(__bf16)a[1]; h[2]=(__bf16)a[2]; h[3]=(__bf16)a[3];
    h[4]=(__bf16)b[0]; h[5]=(__bf16)b[1]; h[6]=(__bf16)b[2]; h[7]=(__bf16)b[3];
    *(bf16x8*)swz(X, r, 256, c*16) = h;
  }
  for (int t = tid; t < 512; t += 256){            // memory: 32 rows x 16 chunks
    int r = t >> 4, c8 = (t & 15)*8;
    const float* gp = memory + (size_t)(b0 + (r>>3))*1024 + (r&7)*128 + c8;
    f32x4 a = *(const f32x4*)gp, b = *(const f32x4*)(gp+4);
    bf16x8 h;
    h[0]=(__bf16)a[0]; h[1]=(__bf16)a[1]; h[2]=(__bf16)a[2]; h[3]=(__bf16)a[3];
    h[4]=(__bf16)b[0]; h[5]=(__bf16)b[1]; h[6]=(__bf16)b[2]; h[7]=(__bf16)b[3];
    *(bf16x8*)swz(A, (r>>3)*S1 + (r&7), 256, c8*2) = h;
  }
  __syncthreads();

  // ---- P1: x = inputs @ W_in + b_in   (M=4 valid rows, clamped A-tile) ----
  {
    const int xr = (l15 < BT) ? l15 : (BT-1);
    bf16x8 aX[4];
#pragma unroll
    for (int k=0;k<4;k++) aX[k] = *(const bf16x8*)swz(X, xr, 256, k*64 + lg*16);
    f32x4 accX[2];
#pragma unroll
    for (int n=0;n<2;n++){
      int nt = wv*2 + n;
      f32x4 acc = {0.f,0.f,0.f,0.f};
#pragma unroll
      for (int k=0;k<4;k++){
        bf16x8 b = *(const bf16x8*)(wWin + (nt*16 + l15)*128 + k*32 + 8*lg);
        acc = __builtin_amdgcn_mfma_f32_16x16x32_bf16(aX[k], b, acc, 0, 0, 0);
      }
      accX[n] = acc;
    }
    __syncthreads();   // all A-reads of X done before overwrite
#pragma unroll
    for (int n=0;n<2;n++){
#pragma unroll
      for (int r=0;r<4;r++){
        int row = 4*lg + r;
        if (row < BT){
          int col = (wv*2+n)*16 + l15;
          __bf16 h = (__bf16)(accX[n][r] + b_in[col]);
          *(bf16s*)swz(X, row, 256, col*2) = h;            // x (for gi GEMM)
          *(bf16s*)swz(A, row*S1+8, 256, col*2) = h;       // mp slot 8
        }
      }
    }
  }
  __syncthreads();

  // ---- P2: qkv_pre = mp @ W_qkv + b_qkv  (M=36, clamped A rows; n-loop halved) ----
  {
    bf16x8 aQ[3][4];
#pragma unroll
    for (int m=0;m<3;m++){
      int ar = m*16 + l15; ar = (ar < RROWS) ? ar : (RROWS-1);
#pragma unroll
      for (int k=0;k<4;k++)
        aQ[m][k] = *(const bf16x8*)swz(A, ar, 256, k*64 + lg*16);
    }
#pragma unroll
    for (int half=0; half<2; ++half){
      f32x4 accQ[3][3];
#pragma unroll
      for (int m=0;m<3;m++)
#pragma unroll
        for (int n=0;n<3;n++) accQ[m][n] = (f32x4){0.f,0.f,0.f,0.f};
#pragma unroll
      for (int n=0;n<3;n++){
        int nt = wv*6 + half*3 + n;
#pragma unroll
        for (int k=0;k<4;k++){
          bf16x8 b = *(const bf16x8*)(wWqkv + (nt*16 + l15)*128 + k*32 + 8*lg);
#pragma unroll
          for (int m=0;m<3;m++)
            accQ[m][n] = __builtin_amdgcn_mfma_f32_16x16x32_bf16(aQ[m][k], b, accQ[m][n], 0, 0, 0);
        }
      }
#pragma unroll
      for (int m=0;m<3;m++)
#pragma unroll
        for (int n=0;n<3;n++)
#pragma unroll
          for (int r=0;r<4;r++){
            int row = m*16 + 4*lg + r;
            if (row < RROWS){
              int col = (wv*6 + half*3 + n)*16 + l15;
              *(bf16s*)swz(Q, row, 768, col*2) = (__bf16)(accQ[m][n][r] + b_qkv[col]);
            }
          }
    }
  }
  __syncthreads();

  // ---- P3: LN(qkv) in place + fold q-scale 96^-0.5 ----
  {
    float gq[6], bq[6];
#pragma unroll
    for (int t=0;t<6;t++){ gq[t] = lnq_g[lane+64*t]; bq[t] = lnq_b[lane+64*t]; }
    for (int r = wv; r < RROWS; r += 4){
      float x[6]; float s = 0.f, sq = 0.f;
#pragma unroll
      for (int t=0;t<6;t++){
        x[t] = (float)*(const bf16s*)swz(Q, r, 768, (lane + 64*t)*2);
        s += x[t]; sq += x[t]*x[t];
      }
#pragma unroll
      for (int o=1;o<64;o<<=1){ s += __shfl_xor(s,o); sq += __shfl_xor(sq,o); }
      float mean = s * (1.f/384.f);
      float var  = sq * (1.f/384.f) - mean*mean;
      float rs   = rsqrtf(var + 1e-5f);
#pragma unroll
      for (int t=0;t<6;t++){
        int c = lane + 64*t;
        float y = gq[t]*(x[t]-mean)*rs + bq[t];
        if ((c % 96) < 32) y *= QSC;
        *(bf16s*)swz(Q, r, 768, c*2) = (__bf16)y;
      }
    }
  }
  __syncthreads();

  // ---- P4a: QK^T via 4 MFMAs per wave (wave = sample); softmax via 16-lane
  //      shuffles; P stored f32 into the wave's OWN dead q-slices (q consumed). ----
  {
    const int s = wv;
    const int arow = (l15 < 9) ? l15 : 8;          // clamp: valid in-slab rows only
    f32x4 sc[4];
#pragma unroll
    for (int h=0;h<4;h++){
      bf16x8 qa = *(const bf16x8*)swz(Q, s*S1+arow, 768, h*192 + lg*16);
      bf16x8 kb = *(const bf16x8*)swz(Q, s*S1+arow, 768, h*192 + 64 + lg*16);
      sc[h] = __builtin_amdgcn_mfma_f32_16x16x32_bf16(qa, kb, (f32x4){0.f,0.f,0.f,0.f}, 0, 0, 0);
    }
#pragma unroll
    for (int h=0;h<4;h++){
#pragma unroll
      for (int r=0;r<4;r++){
        int row = 4*lg + r;                        // q index
        float v = (l15 < 9) ? sc[h][r] : -1e30f;   // mask dup/pad k BEFORE use
        float mx = v;
#pragma unroll
        for (int o=1;o<16;o<<=1) mx = fmaxf(mx, __shfl_xor(mx, o));
        float p = __expf(v - mx);
        float sm = p;
#pragma unroll
        for (int o=1;o<16;o<<=1) sm += __shfl_xor(sm, o);
        float pn = p / sm;
        if (row < 9 && l15 < 9)
          *(f32s*)swz(Q, s*S1+row, 768, h*192 + l15*4) = pn;   // P -> own q-slice
      }
    }
  }
  __syncthreads();

  // ---- P4b: PV. 576 chunk-tasks (s,h,q,chunk) over 3 passes. Each pass:
  //      accumulate o8 (reads P f32 + V), barrier, write out chunk (overwrites P
  //      bytes — safe: a (s,h,q) group's 4 chunks never straddle a pass). ----
#pragma unroll
  for (int pass=0; pass<3; ++pass){
    int ct = pass*256 + tid;
    float o8[8] = {0.f,0.f,0.f,0.f,0.f,0.f,0.f,0.f};
    int s=0, h=0, q=0, d16=0;
    if (ct < 576){
      s = ct/144; int r2 = ct%144;
      h = r2/36;  int r3 = r2%36;
      q = r3>>2;  d16 = (r3&3)*16;
      int cb = h*192;
#pragma unroll
      for (int k=0;k<9;k++){
        float p = *(const f32s*)swz(Q, s*S1+q, 768, cb + k*4);
        bf16x8 v8 = *(const bf16x8*)swz(Q, s*S1+k, 768, cb + 128 + d16);
#pragma unroll
        for (int e=0;e<8;e++) o8[e] += p*(float)v8[e];
      }
    }
    __syncthreads();
    if (ct < 576){
      bf16x8 ho;
#pragma unroll
      for (int e=0;e<8;e++) ho[e] = (__bf16)o8[e];
      *(bf16x8*)swz(Q, s*S1+q, 768, h*192 + d16) = ho;   // out -> q-slice chunk
    }
    __syncthreads();
  }

  // ---- P5: mem = LN(mp + out) -> A in place ----
  {
    float g0 = ln1_g[lane], g1 = ln1_g[lane+64], e0 = ln1_b[lane], e1 = ln1_b[lane+64];
    const int ob0 = (lane>>5)*192 + (lane&31)*2;          // out elem `lane`
    const int ob1 = ((lane>>5)+2)*192 + (lane&31)*2;      // out elem `lane+64`
    for (int r = wv; r < RROWS; r += 4){
      float t0 = (float)*(const bf16s*)swz(A, r, 256, lane*2)
               + (float)*(const bf16s*)swz(Q, r, 768, ob0);
      float t1 = (float)*(const bf16s*)swz(A, r, 256, (lane+64)*2)
               + (float)*(const bf16s*)swz(Q, r, 768, ob1);
      float s = t0+t1, sq = t0*t0 + t1*t1;
#pragma unroll
      for (int o=1;o<64;o<<=1){ s += __shfl_xor(s,o); sq += __shfl_xor(sq,o); }
      float mean = s*(1.f/128.f), var = sq*(1.f/128.f) - mean*mean;
      float rs = rsqrtf(var + 1e-5f);
      *(bf16s*)swz(A, r, 256, lane*2)      = (__bf16)(g0*(t0-mean)*rs + e0);
      *(bf16s*)swz(A, r, 256, (lane+64)*2) = (__bf16)(g1*(t1-mean)*rs + e1);
    }
  }
  __syncthreads();

  // ---- P6: mlp = mem @ (W_m1 W_m2) + bc -> Q f32 [36][512] swz (clamped A rows) ----
  {
    bf16x8 aM[3][4];
#pragma unroll
    for (int m=0;m<3;m++){
      int ar = m*16 + l15; ar = (ar < RROWS) ? ar : (RROWS-1);
#pragma unroll
      for (int k=0;k<4;k++)
        aM[m][k] = *(const bf16x8*)swz(A, ar, 256, k*64 + lg*16);
    }
    f32x4 accM[3][2];
#pragma unroll
    for (int m=0;m<3;m++)
#pragma unroll
      for (int n=0;n<2;n++) accM[m][n] = (f32x4){0.f,0.f,0.f,0.f};
#pragma unroll
    for (int n=0;n<2;n++){
      int nt = wv*2 + n;
#pragma unroll
      for (int k=0;k<4;k++){
        bf16x8 b = *(const bf16x8*)(wWc + (nt*16 + l15)*128 + k*32 + 8*lg);
#pragma unroll
        for (int m=0;m<3;m++)
          accM[m][n] = __builtin_amdgcn_mfma_f32_16x16x32_bf16(aM[m][k], b, accM[m][n], 0, 0, 0);
      }
    }
    __syncthreads();   // Q (qkv+out) fully consumed (P5) before overwrite as mlp
#pragma unroll
    for (int m=0;m<3;m++)
#pragma unroll
      for (int n=0;n<2;n++)
#pragma unroll
        for (int r=0;r<4;r++){
          int row = m*16 + 4*lg + r;
          if (row < RROWS){
            int col = (wv*2+n)*16 + l15;
            *(f32s*)swz(Q, row, 512, col*4) = accM[m][n][r] + bc[col];
          }
        }
  }
  __syncthreads();

  // ---- P7: mem2 = LN(mlp + mem) -> Q+MEM2 bf16 compact [32][256] (skip slot-8) ----
  {
    float g0 = ln2_g[lane], g1 = ln2_g[lane+64], e0 = ln2_b[lane], e1 = ln2_b[lane+64];
    for (int r = wv; r < RROWS; r += 4){
      if ((r % S1) == 8) continue;
      float t0 = *(const f32s*)swz(Q, r, 512, lane*4)
               + (float)*(const bf16s*)swz(A, r, 256, lane*2);
      float t1 = *(const f32s*)swz(Q, r, 512, (lane+64)*4)
               + (float)*(const bf16s*)swz(A, r, 256, (lane+64)*2);
      float s = t0+t1, sq = t0*t0 + t1*t1;
#pragma unroll
      for (int o=1;o<64;o<<=1){ s += __shfl_xor(s,o); sq += __shfl_xor(sq,o); }
      float mean = s*(1.f/128.f), var = sq*(1.f/128.f) - mean*mean;
      float rs = rsqrtf(var + 1e-5f);
      int rp = (r/S1)*8 + (r%S1);                          // compact row s*8+j
      *(bf16s*)swz(Q + MEM2, rp, 256, lane*2)      = (__bf16)(g0*(t0-mean)*rs + e0);
      *(bf16s*)swz(Q + MEM2, rp, 256, (lane+64)*2) = (__bf16)(g1*(t1-mean)*rs + e1);
    }
  }
  __syncthreads();

  // ---- P8: gi = x @ W_gi + b_gi -> gib f32 [4][1024] @Q (over dead mlp);
  //          tanh(memory) -> A compact rows 0..31 ----
  {
    const int xr = (l15 < BT) ? l15 : (BT-1);
    bf16x8 aG[4];
#pragma unroll
    for (int k=0;k<4;k++) aG[k] = *(const bf16x8*)swz(X, xr, 256, k*64 + lg*16);
    f32x4 accG[4];
#pragma unroll
    for (int n=0;n<4;n++) accG[n] = (f32x4){0.f,0.f,0.f,0.f};
#pragma unroll
    for (int n=0;n<4;n++){
      int nt = wv*4 + n;
#pragma unroll
      for (int k=0;k<4;k++){
        bf16x8 b = *(const bf16x8*)(wWgi + (nt*16 + l15)*128 + k*32 + 8*lg);
        accG[n] = __builtin_amdgcn_mfma_f32_16x16x32_bf16(aG[k], b, accG[n], 0, 0, 0);
      }
    }
#pragma unroll
    for (int n=0;n<4;n++)
#pragma unroll
      for (int r=0;r<4;r++){
        int row = 4*lg + r;
        if (row < BT){
          int col = (wv*4+n)*16 + l15;
          *(f32s*)swz(Q, row, 1024, col*4) = accG[n][r] + b_gi[col];
        }
      }
    for (int t = tid; t < 512; t += 256){
      int r = t >> 4, c8 = (t & 15)*8;
      const float* gp = memory + (size_t)(b0 + (r>>3))*1024 + (r&7)*128 + c8;
      f32x4 a = *(const f32x4*)gp, b = *(const f32x4*)(gp+4);
      bf16x8 h;
      h[0]=(__bf16)tanhf_(a[0]); h[1]=(__bf16)tanhf_(a[1]);
      h[2]=(__bf16)tanhf_(a[2]); h[3]=(__bf16)tanhf_(a[3]);
      h[4]=(__bf16)tanhf_(b[0]); h[5]=(__bf16)tanhf_(b[1]);
      h[6]=(__bf16)tanhf_(b[2]); h[7]=(__bf16)tanhf_(b[3]);
      *(bf16x8*)swz(A, r, 256, c8*2) = h;
    }
  }
  __syncthreads();

  // ---- P9: gm = tanh(memory) @ W_gm + b_gm; fused gates -> global.
  //      Re-looped (m outer, p inner, epilogue immediate): peak ~40 VALU regs. ----
  {
#pragma unroll
    for (int m=0;m<2;m++){
      bf16x8 aT[4];
#pragma unroll
      for (int k=0;k<4;k++)
        aT[k] = *(const bf16x8*)swz(A, m*16 + l15, 256, k*64 + lg*16);
#pragma unroll
      for (int p=0;p<2;p++){
        f32x4 ai = {0.f,0.f,0.f,0.f}, af = {0.f,0.f,0.f,0.f};
        int ntI = 2*wv + p, ntF = 8 + 2*wv + p;
#pragma unroll
        for (int k=0;k<4;k++){
          bf16x8 bI = *(const bf16x8*)(wWgm + (ntI*16 + l15)*128 + k*32 + 8*lg);
          bf16x8 bF = *(const bf16x8*)(wWgm + (ntF*16 + l15)*128 + k*32 + 8*lg);
          ai = __builtin_amdgcn_mfma_f32_16x16x32_bf16(aT[k], bI, ai, 0, 0, 0);
          af = __builtin_amdgcn_mfma_f32_16x16x32_bf16(aT[k], bF, af, 0, 0, 0);
        }
        int c = wv*32 + p*16 + l15;
        float giv = *(const f32s*)swz(Q, 0, 1024, 0) * 0.f;  // (dead; keep layout simple)
        giv = *(const f32s*)swz(Q, 0, 1024, c*4);            // gib row computed per s below
        float bgi = b_gm[c], bgf = b_gm[128+c];
#pragma unroll
        for (int r=0;r<4;r++){
          int row = m*16 + 4*lg + r;       // 0..31 = s*8+j
          int s = row>>3, j = row&7;
          float g_i = ai[r] + bgi + *(const f32s*)swz(Q, s, 1024, c*4);
          float g_f = af[r] + bgf + *(const f32s*)swz(Q, s, 1024, (128+c)*4) + 1.0f;
          float ig = sigmoidf_(g_i), fg = sigmoidf_(g_f);
          float m2 = (float)*(const bf16s*)swz(Q + MEM2, row, 256, c*2);
          float mo = memory[(size_t)(b0+s)*1024 + j*128 + c];
          float nm = ig*tanhf_(m2) + fg*mo;
          size_t o = (size_t)(b0+s)*1024 + (size_t)(j*128 + c);
          out0[o] = nm;
          out1[o] = nm;
        }
      }
    }
  }
}

// ---------------- launch ----------------
extern "C" void kernel_launch(void* const* d_in, const int* in_sizes, int n_in,
                              void* d_out, int out_size, void* d_ws, size_t ws_size,
                              hipStream_t stream) {
  const float* inputs = (const float*)d_in[0];
  const float* memory = (const float*)d_in[1];
  const float* W_in   = (const float*)d_in[2];
  const float* b_in   = (const float*)d_in[3];
  const float* W_qkv  = (const float*)d_in[4];
  const float* b_qkv  = (const float*)d_in[5];
  const float* lnq_g  = (const float*)d_in[6];
  const float* lnq_b  = (const float*)d_in[7];
  const float* ln1_g  = (const float*)d_in[8];
  const float* ln1_b  = (const float*)d_in[9];
  const float* W_m1   = (const float*)d_in[10];
  const float* b_m1   = (const float*)d_in[11];
  const float* W_m2   = (const float*)d_in[12];
  const float* b_m2   = (const float*)d_in[13];
  const float* ln2_g  = (const float*)d_in[14];
  const float* ln2_b  = (const float*)d_in[15];
  const float* W_gi   = (const float*)d_in[16];
  const float* b_gi   = (const float*)d_in[17];
  const float* W_gm   = (const float*)d_in[18];
  const float* b_gm   = (const float*)d_in[19];

  __bf16* ws16 = (__bf16*)d_ws;
  float* bcp = (float*)((char*)d_ws + WS_BC);
  const __bf16* wWin  = (const __bf16*)((char*)d_ws + WS_WIN);
  const __bf16* wWqkv = (const __bf16*)((char*)d_ws + WS_WQKV);
  const __bf16* wWc   = (const __bf16*)((char*)d_ws + WS_WC);
  const __bf16* wWgi  = (const __bf16*)((char*)d_ws + WS_WGI);
  const __bf16* wWgm  = (const __bf16*)((char*)d_ws + WS_WGM);

  float* out0 = (float*)d_out;
  float* out1 = out0 + (size_t)BATCH*1024;

  prep_kernel<<<dim3(256), dim3(256), 0, stream>>>(
      W_in, W_qkv, W_m1, W_m2, b_m1, b_m2, W_gi, W_gm, ws16, bcp);

  rmc_kernel<<<dim3(NBLK), dim3(256), 0, stream>>>(
      inputs, memory, b_in, b_qkv, lnq_g, lnq_b, ln1_g, ln1_b, ln2_g, ln2_b,
      b_gi, b_gm, wWin, wWqkv, wWc, wWgi, wWgm, bcp, out0, out1);
}